// Round 1
// baseline (378.670 us; speedup 1.0000x reference)
//
#include <hip/hip_runtime.h>
#include <cstdint>
#include <cstddef>

#define S_LEN 2048
#define DIN   512
#define DOUT  64
#define NB    4
#define NH    8

typedef __attribute__((ext_vector_type(8))) short bf16x8;
typedef __attribute__((ext_vector_type(4))) float f32x4;

static __device__ __forceinline__ f32x4 mfma16(bf16x8 a, bf16x8 b, f32x4 c) {
    return __builtin_amdgcn_mfma_f32_16x16x32_bf16(a, b, c, 0, 0, 0);
}

static __device__ __forceinline__ uint16_t f2bf(float x) {
    uint32_t u = __builtin_bit_cast(uint32_t, x);
    u += 0x7fffu + ((u >> 16) & 1u);
    return (uint16_t)(u >> 16);
}
static __device__ __forceinline__ float bf2f(uint16_t h) {
    uint32_t u = ((uint32_t)h) << 16;
    return __builtin_bit_cast(float, u);
}

// ---------------------------------------------------------------------------
// Kernel 1: transpose + hi/lo-split weights.
//   w  [H][3][512][64] fp32 -> whiT/wloT [24][64][512] bf16 (q-weights pre-scaled
//   by 0.125*log2(e) so flash softmax is exp2-native)
//   wo [512][64] fp32       -> woT [64][512] bf16
// ---------------------------------------------------------------------------
__global__ __launch_bounds__(256) void prep_w(
    const float* __restrict__ w, const float* __restrict__ wo,
    uint16_t* __restrict__ whiT, uint16_t* __restrict__ wloT,
    uint16_t* __restrict__ woT)
{
    const int blk = blockIdx.x;   // 0..23 = (h*3+p); 24 = wo
    const int t = threadIdx.x;
    if (blk < 24) {
        const int p = blk % 3;
        const float s = (p == 0) ? 0.18033688011112042f : 1.0f; // 0.125*log2e
        const float* __restrict__ wsrc = w + (size_t)blk * (DIN * DOUT);
        uint16_t* __restrict__ dh = whiT + (size_t)blk * (DOUT * DIN);
        uint16_t* __restrict__ dl = wloT + (size_t)blk * (DOUT * DIN);
        for (int it = 0; it < 128; ++it) {
            const int idx = it * 256 + t;        // = o*512 + i
            const int o = idx >> 9, i = idx & 511;
            const float x = wsrc[i * DOUT + o] * s;
            const uint16_t hi = f2bf(x);
            dh[idx] = hi;
            dl[idx] = f2bf(x - bf2f(hi));
        }
    } else {
        for (int it = 0; it < 128; ++it) {
            const int idx = it * 256 + t;
            const int o = idx >> 9, i = idx & 511;
            woT[idx] = f2bf(wo[i * DOUT + o]);
        }
    }
}

// ---------------------------------------------------------------------------
// Kernel 2: QKV projection, bf16x3 split precision.
//   out[m][n] = sum_k x[m][k] * w[hp][k][n],  M=8192, K=512, N=64 per (h,p)
//   grid (24 hp, 128 mtiles); 4 waves, each 16 rows x 64 cols.
//   Writes qhi/qlo/khi/klo/v as [B*H][S][64] bf16.
// ---------------------------------------------------------------------------
__global__ __launch_bounds__(256) void proj_qkv(
    const float* __restrict__ x,
    const uint16_t* __restrict__ whiT, const uint16_t* __restrict__ wloT,
    uint16_t* __restrict__ qhi, uint16_t* __restrict__ qlo,
    uint16_t* __restrict__ khi, uint16_t* __restrict__ klo,
    uint16_t* __restrict__ vbf)
{
    const int hp = blockIdx.x;     // fastest-varying: 24 blocks share one x M-tile
    const int mt = blockIdx.y;
    const int h = hp / 3, p = hp % 3;
    const int tid = threadIdx.x;
    const int l = tid & 63, w = tid >> 6;
    const int g = l >> 4, lm = l & 15;
    const int m0 = mt * 64 + w * 16;

    const uint16_t* __restrict__ bhp = whiT + (size_t)hp * (DOUT * DIN);
    const uint16_t* __restrict__ blp = wloT + (size_t)hp * (DOUT * DIN);

    const f32x4 Z = {0.f, 0.f, 0.f, 0.f};
    f32x4 acc[4] = {Z, Z, Z, Z};

    const float* __restrict__ xrow = x + (size_t)(m0 + lm) * DIN;

    for (int kc = 0; kc < 16; ++kc) {
        const float* xp = xrow + kc * 32 + g * 8;
        const float4 x0 = *(const float4*)xp;
        const float4 x1 = *(const float4*)(xp + 4);
        const float xv[8] = {x0.x, x0.y, x0.z, x0.w, x1.x, x1.y, x1.z, x1.w};
        bf16x8 ah, al;
        #pragma unroll
        for (int j = 0; j < 8; ++j) {
            const float v = xv[j];
            const uint16_t hi = f2bf(v);
            ah[j] = (short)hi;
            al[j] = (short)f2bf(v - bf2f(hi));
        }
        #pragma unroll
        for (int nt = 0; nt < 4; ++nt) {
            const size_t boff = (size_t)(nt * 16 + lm) * DIN + kc * 32 + g * 8;
            const bf16x8 bh = *(const bf16x8*)(bhp + boff);
            const bf16x8 bl = *(const bf16x8*)(blp + boff);
            acc[nt] = mfma16(ah, bh, acc[nt]);
            acc[nt] = mfma16(ah, bl, acc[nt]);
            acc[nt] = mfma16(al, bh, acc[nt]);
        }
    }

    const int b = m0 >> 11;
    const int srow0 = (m0 & 2047) + 4 * g;
    uint16_t* __restrict__ dhi = (p == 0) ? qhi : khi;
    uint16_t* __restrict__ dlo = (p == 0) ? qlo : klo;
    const size_t tb = (size_t)(b * NH + h) * S_LEN;
    #pragma unroll
    for (int nt = 0; nt < 4; ++nt) {
        #pragma unroll
        for (int j = 0; j < 4; ++j) {
            const size_t idx = (tb + srow0 + j) * DOUT + nt * 16 + lm;
            const float v = acc[nt][j];
            if (p < 2) {
                const uint16_t hi = f2bf(v);
                dhi[idx] = hi;
                dlo[idx] = f2bf(v - bf2f(hi));
            } else {
                vbf[idx] = f2bf(v);
            }
        }
    }
}

// ---------------------------------------------------------------------------
// Kernel 3: flash attention forward.
//   grid (32 qtiles, 32 bh); 4 waves/block, 16 q-rows/wave, KV tiles of 64.
//   Swapped QK^T (mfma(K,Q)) -> per-lane q (= lane&15), k spread over regs/groups.
//   bf16 hi/lo x3 for QK; plain bf16 P,V for PV. XOR-swizzled LDS everywhere.
// ---------------------------------------------------------------------------
__global__ __launch_bounds__(256) void attn_fwd(
    const uint16_t* __restrict__ qhi, const uint16_t* __restrict__ qlo,
    const uint16_t* __restrict__ khi, const uint16_t* __restrict__ klo,
    const uint16_t* __restrict__ vbf, uint16_t* __restrict__ oc)
{
    __shared__ __align__(16) char smem[32768];
    char* __restrict__ kh_lds = smem;            // [64][64] bf16 swizzled, 8 KB
    char* __restrict__ kl_lds = smem + 8192;     // 8 KB
    char* __restrict__ vt_lds = smem + 16384;    // V^T [64 d][64 kv] swizzled, 8 KB
    char* __restrict__ p_lds  = smem + 24576;    // 4 waves x [16 q][64 k], 8 KB

    const int qt = blockIdx.x, bh = blockIdx.y;
    const int tid = threadIdx.x;
    const int l = tid & 63, w = tid >> 6;
    const int g = l >> 4, lm = l & 15;
    const size_t base = (size_t)bh * (S_LEN * DOUT);

    // Q fragments (B-operand): lane holds Q[q=lm][d = 32c + 8g + j]
    const int qrow = qt * 64 + w * 16 + lm;
    const uint16_t* qp  = qhi + base + (size_t)qrow * DOUT;
    const uint16_t* qlp = qlo + base + (size_t)qrow * DOUT;
    const bf16x8 qh0 = *(const bf16x8*)(qp + g * 8);
    const bf16x8 qh1 = *(const bf16x8*)(qp + 32 + g * 8);
    const bf16x8 ql0 = *(const bf16x8*)(qlp + g * 8);
    const bf16x8 ql1 = *(const bf16x8*)(qlp + 32 + g * 8);

    const f32x4 Z = {0.f, 0.f, 0.f, 0.f};
    f32x4 O[4] = {Z, Z, Z, Z};
    float m_run = -INFINITY, l_run = 0.f;

    const int skv = tid >> 3, ckv = tid & 7;          // K staging map
    const int vkv = tid & 31, vdc = (tid >> 5) & 7;   // V staging map
    char* __restrict__ pb = p_lds + w * 2048;
    const uint32_t pswz = (uint32_t)((lm & 7) << 4);

    for (int kt = 0; kt < 32; ++kt) {
        const int s0 = kt * 64;
        // ---- stage K hi/lo, row-major [kv][d], swizzle byte ^= (kv&7)<<4
        #pragma unroll
        for (int it = 0; it < 2; ++it) {
            const int kv = skv + it * 32;
            const uint32_t off = ((uint32_t)(kv * 128 + ckv * 16)) ^ (uint32_t)((kv & 7) << 4);
            *(uint4*)(kh_lds + off) = *(const uint4*)(khi + base + (size_t)(s0 + kv) * DOUT + ckv * 8);
            *(uint4*)(kl_lds + off) = *(const uint4*)(klo + base + (size_t)(s0 + kv) * DOUT + ckv * 8);
        }
        // ---- stage V transposed: Vt[d][kv], swizzle byte ^= (d&7)<<4
        #pragma unroll
        for (int it = 0; it < 2; ++it) {
            const int kv = vkv + it * 32;
            const uint4 vv = *(const uint4*)(vbf + base + (size_t)(s0 + kv) * DOUT + vdc * 8);
            const uint16_t* ve = (const uint16_t*)&vv;
            #pragma unroll
            for (int j = 0; j < 8; ++j) {
                const int d = vdc * 8 + j;
                const uint32_t off = ((uint32_t)(d * 128 + kv * 2)) ^ (uint32_t)((d & 7) << 4);
                *(uint16_t*)(vt_lds + off) = ve[j];
            }
        }
        __syncthreads();

        // ---- QK^T (swapped): S^T[64k x 16q]; lane has q=lm, k = 16t + 4g + j
        f32x4 sa[4];
        #pragma unroll
        for (int t = 0; t < 4; ++t) {
            f32x4 a = Z;
            const int kr = t * 16 + lm;
            const uint32_t swz = (uint32_t)((kr & 7) << 4);
            {
                const uint32_t off = ((uint32_t)(kr * 128 + g * 16)) ^ swz;
                const bf16x8 kh = *(const bf16x8*)(kh_lds + off);
                const bf16x8 kl = *(const bf16x8*)(kl_lds + off);
                a = mfma16(kh, qh0, a);
                a = mfma16(kh, ql0, a);
                a = mfma16(kl, qh0, a);
            }
            {
                const uint32_t off = ((uint32_t)(kr * 128 + 64 + g * 16)) ^ swz;
                const bf16x8 kh = *(const bf16x8*)(kh_lds + off);
                const bf16x8 kl = *(const bf16x8*)(kl_lds + off);
                a = mfma16(kh, qh1, a);
                a = mfma16(kh, ql1, a);
                a = mfma16(kl, qh1, a);
            }
            sa[t] = a;
        }

        // ---- online softmax (exp2-domain; scale pre-folded into q-weights)
        float tmax = sa[0][0];
        #pragma unroll
        for (int t = 0; t < 4; ++t)
            #pragma unroll
            for (int j = 0; j < 4; ++j) tmax = fmaxf(tmax, sa[t][j]);
        tmax = fmaxf(tmax, __shfl_xor(tmax, 16));
        tmax = fmaxf(tmax, __shfl_xor(tmax, 32));
        const float m_new = fmaxf(m_run, tmax);
        const float alpha = __builtin_amdgcn_exp2f(m_run - m_new);
        m_run = m_new;

        float lsum = 0.f;
        uint32_t pk[8];
        #pragma unroll
        for (int t = 0; t < 4; ++t) {
            const float p0 = __builtin_amdgcn_exp2f(sa[t][0] - m_new);
            const float p1 = __builtin_amdgcn_exp2f(sa[t][1] - m_new);
            const float p2 = __builtin_amdgcn_exp2f(sa[t][2] - m_new);
            const float p3 = __builtin_amdgcn_exp2f(sa[t][3] - m_new);
            lsum += (p0 + p1) + (p2 + p3);
            pk[2 * t]     = (uint32_t)f2bf(p0) | ((uint32_t)f2bf(p1) << 16);
            pk[2 * t + 1] = (uint32_t)f2bf(p2) | ((uint32_t)f2bf(p3) << 16);
        }
        lsum += __shfl_xor(lsum, 16);
        lsum += __shfl_xor(lsum, 32);
        l_run = l_run * alpha + lsum;

        // ---- P -> wave-private LDS [q][k] bf16 (swizzle byte ^= (q&7)<<4)
        #pragma unroll
        for (int t = 0; t < 4; ++t) {
            const uint32_t off = ((uint32_t)(lm * 128 + t * 32 + g * 8)) ^ pswz;
            uint2 val; val.x = pk[2 * t]; val.y = pk[2 * t + 1];
            *(uint2*)(pb + off) = val;
        }
        asm volatile("s_waitcnt lgkmcnt(0)" ::: "memory");
        __builtin_amdgcn_sched_barrier(0);

        // ---- rescale O by alpha (per O-row q = 4g + j)
        const float av0 = __shfl(alpha, 4 * g + 0);
        const float av1 = __shfl(alpha, 4 * g + 1);
        const float av2 = __shfl(alpha, 4 * g + 2);
        const float av3 = __shfl(alpha, 4 * g + 3);
        const f32x4 am = {av0, av1, av2, av3};
        #pragma unroll
        for (int dt = 0; dt < 4; ++dt) O[dt] *= am;

        // ---- PV: O[16q x 64d] += P[16q x 64k] * V[64k x 64d]
        #pragma unroll
        for (int kc = 0; kc < 2; ++kc) {
            const uint32_t poff = ((uint32_t)(lm * 128 + kc * 64 + g * 16)) ^ pswz;
            const bf16x8 pa = *(const bf16x8*)(pb + poff);
            #pragma unroll
            for (int dt = 0; dt < 4; ++dt) {
                const int vr = dt * 16 + lm;
                const uint32_t voff = ((uint32_t)(vr * 128 + kc * 64 + g * 16)) ^ pswz;
                const bf16x8 vb = *(const bf16x8*)(vt_lds + voff);
                O[dt] = mfma16(pa, vb, O[dt]);
            }
        }
        __syncthreads();
    }

    // ---- epilogue: normalize, write o_concat[b][s][h*64+d] bf16
    const int b = bh >> 3, hh = bh & 7;
    #pragma unroll
    for (int j = 0; j < 4; ++j) {
        const float li = 1.f / __shfl(l_run, 4 * g + j);
        const int srow = qt * 64 + w * 16 + 4 * g + j;
        const size_t rbase = ((size_t)b * S_LEN + srow) * (NH * DOUT) + hh * DOUT;
        #pragma unroll
        for (int dt = 0; dt < 4; ++dt)
            oc[rbase + dt * 16 + lm] = f2bf(O[dt][j] * li);
    }
}

// ---------------------------------------------------------------------------
// Kernel 4: output projection out = o_concat[8192x512] @ wo[512x64], fp32 out.
// ---------------------------------------------------------------------------
__global__ __launch_bounds__(256) void oproj(
    const uint16_t* __restrict__ oc, const uint16_t* __restrict__ woT,
    float* __restrict__ out)
{
    const int mt = blockIdx.x;
    const int tid = threadIdx.x;
    const int l = tid & 63, w = tid >> 6;
    const int g = l >> 4, lm = l & 15;
    const int m0 = mt * 64 + w * 16;
    const f32x4 Z = {0.f, 0.f, 0.f, 0.f};
    f32x4 acc[4] = {Z, Z, Z, Z};
    const uint16_t* __restrict__ arow = oc + (size_t)(m0 + lm) * (NH * DOUT);
    for (int kc = 0; kc < 16; ++kc) {
        const bf16x8 a = *(const bf16x8*)(arow + kc * 32 + g * 8);
        #pragma unroll
        for (int nt = 0; nt < 4; ++nt) {
            const bf16x8 bfr = *(const bf16x8*)(woT + (size_t)(nt * 16 + lm) * (NH * DOUT) + kc * 32 + g * 8);
            acc[nt] = mfma16(a, bfr, acc[nt]);
        }
    }
    #pragma unroll
    for (int nt = 0; nt < 4; ++nt)
        #pragma unroll
        for (int j = 0; j < 4; ++j)
            out[(size_t)(m0 + 4 * g + j) * DOUT + nt * 16 + lm] = acc[nt][j];
}

// ---------------------------------------------------------------------------
extern "C" void kernel_launch(void* const* d_in, const int* in_sizes, int n_in,
                              void* d_out, int out_size, void* d_ws, size_t ws_size,
                              hipStream_t stream) {
    const float* x  = (const float*)d_in[0];
    const float* w  = (const float*)d_in[1];
    const float* wo = (const float*)d_in[2];
    float* out = (float*)d_out;

    char* ws = (char*)d_ws;
    // [B*H][S][64] bf16 tensors: 4*8*2048*64*2 = 8388608 B each
    uint16_t* qhi  = (uint16_t*)(ws);
    uint16_t* qlo  = (uint16_t*)(ws + 8388608);
    uint16_t* khi  = (uint16_t*)(ws + 16777216);
    uint16_t* klo  = (uint16_t*)(ws + 25165824);
    uint16_t* vbf  = (uint16_t*)(ws + 33554432);
    uint16_t* oc   = (uint16_t*)(ws + 41943040);   // [B][S][512] bf16, 8388608 B
    uint16_t* whiT = (uint16_t*)(ws + 50331648);   // [24][64][512] bf16
    uint16_t* wloT = (uint16_t*)(ws + 51904512);
    uint16_t* woT  = (uint16_t*)(ws + 53477376);   // [64][512] bf16
    // total: 53542912 B (~51 MB)

    hipLaunchKernelGGL(prep_w, dim3(25), dim3(256), 0, stream, w, wo, whiT, wloT, woT);
    hipLaunchKernelGGL(proj_qkv, dim3(24, 128), dim3(256), 0, stream,
                       x, whiT, wloT, qhi, qlo, khi, klo, vbf);
    hipLaunchKernelGGL(attn_fwd, dim3(32, 32), dim3(256), 0, stream,
                       qhi, qlo, khi, klo, vbf, oc);
    hipLaunchKernelGGL(oproj, dim3(128), dim3(256), 0, stream, oc, woT, out);
}

// Round 2
// 207.094 us; speedup vs baseline: 1.8285x; 1.8285x over previous
//
#include <hip/hip_runtime.h>
#include <cstdint>
#include <cstddef>

#define S_LEN 2048
#define DIN   512
#define DOUT  64
#define NB    4
#define NH    8

typedef __attribute__((ext_vector_type(8))) short bf16x8;
typedef __attribute__((ext_vector_type(4))) float f32x4;

static __device__ __forceinline__ f32x4 mfma16(bf16x8 a, bf16x8 b, f32x4 c) {
    return __builtin_amdgcn_mfma_f32_16x16x32_bf16(a, b, c, 0, 0, 0);
}

static __device__ __forceinline__ uint16_t f2bf(float x) {
    uint32_t u = __builtin_bit_cast(uint32_t, x);
    u += 0x7fffu + ((u >> 16) & 1u);
    return (uint16_t)(u >> 16);
}
static __device__ __forceinline__ float bf2f(uint16_t h) {
    uint32_t u = ((uint32_t)h) << 16;
    return __builtin_bit_cast(float, u);
}

typedef const __attribute__((address_space(1))) void* as1p;
typedef __attribute__((address_space(3))) void* as3p;
static __device__ __forceinline__ void gload_lds16(const void* g, void* l) {
    __builtin_amdgcn_global_load_lds((as1p)g, (as3p)l, 16, 0, 0);
}

// ---------------------------------------------------------------------------
// Kernel 1: weight prep via LDS transpose (coalesced both sides).
//   blocks 0..191: (hp, i-tile) of w [24][512][64] -> whiT/wloT [1536][512] bf16
//                  (q-weights pre-scaled by 0.125*log2e for exp2-native softmax)
//   blocks 192..199: wo [512][64] -> woT [64][512] bf16
// ---------------------------------------------------------------------------
__global__ __launch_bounds__(256) void prep_w(
    const float* __restrict__ w, const float* __restrict__ wo,
    uint16_t* __restrict__ whiT, uint16_t* __restrict__ wloT,
    uint16_t* __restrict__ woT)
{
    __shared__ float tile[64][65];
    const int blk = blockIdx.x;
    const int t = threadIdx.x;
    const int tq = t >> 6, tr = t & 63;

    if (blk < 192) {
        const int hp = blk >> 3, i0 = (blk & 7) * 64;
        const int p = hp % 3;
        const float s = (p == 0) ? 0.18033688011112042f : 1.0f; // 0.125*log2(e)
        const float* __restrict__ src = w + (size_t)hp * (DIN * DOUT);
        #pragma unroll
        for (int r = 0; r < 16; ++r) {
            const int ir = r * 4 + tq;
            tile[ir][tr] = src[(size_t)(i0 + ir) * DOUT + tr];
        }
        __syncthreads();
        uint16_t* __restrict__ dh = whiT + (size_t)hp * (DOUT * DIN);
        uint16_t* __restrict__ dl = wloT + (size_t)hp * (DOUT * DIN);
        #pragma unroll
        for (int r = 0; r < 16; ++r) {
            const int o = r * 4 + tq;
            const float v = tile[tr][o] * s;
            const uint16_t hi = f2bf(v);
            dh[(size_t)o * DIN + i0 + tr] = hi;
            dl[(size_t)o * DIN + i0 + tr] = f2bf(v - bf2f(hi));
        }
    } else {
        const int i0 = (blk - 192) * 64;
        #pragma unroll
        for (int r = 0; r < 16; ++r) {
            const int ir = r * 4 + tq;
            tile[ir][tr] = wo[(size_t)(i0 + ir) * DOUT + tr];
        }
        __syncthreads();
        #pragma unroll
        for (int r = 0; r < 16; ++r) {
            const int o = r * 4 + tq;
            woT[(size_t)o * DIN + i0 + tr] = f2bf(tile[tr][o]);
        }
    }
}

// ---------------------------------------------------------------------------
// Kernel 2: split x [8192][512] fp32 -> xhi/xlo bf16 (vectorized, one pass).
// ---------------------------------------------------------------------------
__global__ __launch_bounds__(256) void split_x(
    const float* __restrict__ x, uint16_t* __restrict__ xhi, uint16_t* __restrict__ xlo)
{
    const size_t idx = ((size_t)blockIdx.x * 256 + threadIdx.x) * 8;
    const float4 a = *(const float4*)(x + idx);
    const float4 b = *(const float4*)(x + idx + 4);
    const float xv[8] = {a.x, a.y, a.z, a.w, b.x, b.y, b.z, b.w};
    union { uint16_t u[8]; uint4 v; } H, L;
    #pragma unroll
    for (int j = 0; j < 8; ++j) {
        const uint16_t hi = f2bf(xv[j]);
        H.u[j] = hi;
        L.u[j] = f2bf(xv[j] - bf2f(hi));
    }
    *(uint4*)(xhi + idx) = H.v;
    *(uint4*)(xlo + idx) = L.v;
}

// ---------------------------------------------------------------------------
// Kernel 3: QKV projection as one bf16 GEMM, M=8192 N=1536 K=1536(virtual).
//   K-slabs: [0,512)=xhi*whi, [512,1024)=xhi*wlo, [1024,1536)=xlo*whi.
//   m97 structure: 128x128 tile, BK=64, 4 waves (each 64x64), global_load_lds
//   w=16 with inverse-swizzled source, XOR-swizzled ds_read_b128 (T2),
//   bijective XCD swizzle (T1; 768 blocks = 8 x 96).
//   Epilogue splits q/k into hi/lo bf16, v plain bf16, layout [B*H][S][64].
// ---------------------------------------------------------------------------
__global__ __launch_bounds__(256) void gemm_qkv(
    const uint16_t* __restrict__ xhi, const uint16_t* __restrict__ xlo,
    const uint16_t* __restrict__ whiT, const uint16_t* __restrict__ wloT,
    uint16_t* __restrict__ qhi, uint16_t* __restrict__ qlo,
    uint16_t* __restrict__ khi, uint16_t* __restrict__ klo,
    uint16_t* __restrict__ vbf)
{
    __shared__ __align__(16) uint16_t lds[2 * 128 * 64];   // A tile | B tile, 32 KB

    const int bid = blockIdx.x;
    const int xcd = bid & 7, wi = bid >> 3;
    const int mt = xcd * 8 + wi / 12, nt = wi % 12;
    const int m0 = mt * 128, n0 = nt * 128;
    const int tid = threadIdx.x;
    const int l = tid & 63, w = tid >> 6;
    const int g = l >> 4, lm = l & 15;
    const int wm = w >> 1, wn = w & 1;

    const f32x4 Z = {0.f, 0.f, 0.f, 0.f};
    f32x4 acc[4][4];
    #pragma unroll
    for (int a = 0; a < 4; ++a)
        #pragma unroll
        for (int b = 0; b < 4; ++b) acc[a][b] = Z;

    // staging geometry: chunk c = i*256+tid covers LDS [c*16, c*16+16);
    // row=c>>3, 16B-slot=c&7; global col = (slot*8) ^ ((row&7)<<3) elems
    int srow[4], scol[4];
    #pragma unroll
    for (int i = 0; i < 4; ++i) {
        const int c = i * 256 + tid;
        srow[i] = c >> 3;
        scol[i] = ((c & 7) * 8) ^ ((srow[i] & 7) << 3);
    }

    for (int kt = 0; kt < 24; ++kt) {
        const int k0 = (kt & 7) * 64;
        const uint16_t* __restrict__ As = (kt < 16) ? xhi : xlo;
        const uint16_t* __restrict__ Bs = (kt >= 8 && kt < 16) ? wloT : whiT;
        #pragma unroll
        for (int i = 0; i < 4; ++i) {
            const int c8 = (i * 256 + tid) * 8;
            gload_lds16(As + (size_t)(m0 + srow[i]) * DIN + k0 + scol[i], &lds[c8]);
            gload_lds16(Bs + (size_t)(n0 + srow[i]) * DIN + k0 + scol[i], &lds[128 * 64 + c8]);
        }
        asm volatile("s_waitcnt vmcnt(0)" ::: "memory");
        __syncthreads();

        bf16x8 af[4][2];
        #pragma unroll
        for (int mi = 0; mi < 4; ++mi) {
            const int r = wm * 64 + mi * 16 + lm;
            const int rb = r * 128;
            #pragma unroll
            for (int kk = 0; kk < 2; ++kk) {
                const int cb = (kk * 64 + g * 16) ^ ((r & 7) << 4);
                af[mi][kk] = *(const bf16x8*)((const char*)lds + rb + cb);
            }
        }
        #pragma unroll
        for (int ni = 0; ni < 4; ++ni) {
            const int r = wn * 64 + ni * 16 + lm;
            const int rb = 128 * 64 * 2 + r * 128;
            bf16x8 bfr[2];
            #pragma unroll
            for (int kk = 0; kk < 2; ++kk) {
                const int cb = (kk * 64 + g * 16) ^ ((r & 7) << 4);
                bfr[kk] = *(const bf16x8*)((const char*)lds + rb + cb);
            }
            #pragma unroll
            for (int mi = 0; mi < 4; ++mi) {
                acc[mi][ni] = mfma16(af[mi][0], bfr[0], acc[mi][ni]);
                acc[mi][ni] = mfma16(af[mi][1], bfr[1], acc[mi][ni]);
            }
        }
        __syncthreads();
    }

    // epilogue: n -> (hp = h*3+p, o); write q/k hi+lo, v bf16; [B*H][S][64]
    #pragma unroll
    for (int ni = 0; ni < 4; ++ni) {
        const int n = n0 + wn * 64 + ni * 16 + lm;
        const int hp = n >> 6, o = n & 63;
        const int h = hp / 3, p = hp - h * 3;
        uint16_t* __restrict__ dhi = (p == 0) ? qhi : khi;
        uint16_t* __restrict__ dlo = (p == 0) ? qlo : klo;
        #pragma unroll
        for (int mi = 0; mi < 4; ++mi) {
            #pragma unroll
            for (int j = 0; j < 4; ++j) {
                const int m = m0 + wm * 64 + mi * 16 + 4 * g + j;
                const int b = m >> 11, s = m & 2047;
                const size_t idx = ((size_t)(b * NH + h) * S_LEN + s) * DOUT + o;
                const float v = acc[mi][ni][j];
                if (p < 2) {
                    const uint16_t hi = f2bf(v);
                    dhi[idx] = hi;
                    dlo[idx] = f2bf(v - bf2f(hi));
                } else {
                    vbf[idx] = f2bf(v);
                }
            }
        }
    }
}

// ---------------------------------------------------------------------------
// Kernel 4: flash attention forward (unchanged from R1).
// ---------------------------------------------------------------------------
__global__ __launch_bounds__(256) void attn_fwd(
    const uint16_t* __restrict__ qhi, const uint16_t* __restrict__ qlo,
    const uint16_t* __restrict__ khi, const uint16_t* __restrict__ klo,
    const uint16_t* __restrict__ vbf, uint16_t* __restrict__ oc)
{
    __shared__ __align__(16) char smem[32768];
    char* __restrict__ kh_lds = smem;            // [64][64] bf16 swizzled, 8 KB
    char* __restrict__ kl_lds = smem + 8192;     // 8 KB
    char* __restrict__ vt_lds = smem + 16384;    // V^T [64 d][64 kv] swizzled, 8 KB
    char* __restrict__ p_lds  = smem + 24576;    // 4 waves x [16 q][64 k], 8 KB

    const int qt = blockIdx.x, bh = blockIdx.y;
    const int tid = threadIdx.x;
    const int l = tid & 63, w = tid >> 6;
    const int g = l >> 4, lm = l & 15;
    const size_t base = (size_t)bh * (S_LEN * DOUT);

    const int qrow = qt * 64 + w * 16 + lm;
    const uint16_t* qp  = qhi + base + (size_t)qrow * DOUT;
    const uint16_t* qlp = qlo + base + (size_t)qrow * DOUT;
    const bf16x8 qh0 = *(const bf16x8*)(qp + g * 8);
    const bf16x8 qh1 = *(const bf16x8*)(qp + 32 + g * 8);
    const bf16x8 ql0 = *(const bf16x8*)(qlp + g * 8);
    const bf16x8 ql1 = *(const bf16x8*)(qlp + 32 + g * 8);

    const f32x4 Z = {0.f, 0.f, 0.f, 0.f};
    f32x4 O[4] = {Z, Z, Z, Z};
    float m_run = -INFINITY, l_run = 0.f;

    const int skv = tid >> 3, ckv = tid & 7;
    const int vkv = tid & 31, vdc = (tid >> 5) & 7;
    char* __restrict__ pb = p_lds + w * 2048;
    const uint32_t pswz = (uint32_t)((lm & 7) << 4);

    for (int kt = 0; kt < 32; ++kt) {
        const int s0 = kt * 64;
        #pragma unroll
        for (int it = 0; it < 2; ++it) {
            const int kv = skv + it * 32;
            const uint32_t off = ((uint32_t)(kv * 128 + ckv * 16)) ^ (uint32_t)((kv & 7) << 4);
            *(uint4*)(kh_lds + off) = *(const uint4*)(khi + base + (size_t)(s0 + kv) * DOUT + ckv * 8);
            *(uint4*)(kl_lds + off) = *(const uint4*)(klo + base + (size_t)(s0 + kv) * DOUT + ckv * 8);
        }
        #pragma unroll
        for (int it = 0; it < 2; ++it) {
            const int kv = vkv + it * 32;
            const uint4 vv = *(const uint4*)(vbf + base + (size_t)(s0 + kv) * DOUT + vdc * 8);
            const uint16_t* ve = (const uint16_t*)&vv;
            #pragma unroll
            for (int j = 0; j < 8; ++j) {
                const int d = vdc * 8 + j;
                const uint32_t off = ((uint32_t)(d * 128 + kv * 2)) ^ (uint32_t)((d & 7) << 4);
                *(uint16_t*)(vt_lds + off) = ve[j];
            }
        }
        __syncthreads();

        f32x4 sa[4];
        #pragma unroll
        for (int t = 0; t < 4; ++t) {
            f32x4 a = Z;
            const int kr = t * 16 + lm;
            const uint32_t swz = (uint32_t)((kr & 7) << 4);
            {
                const uint32_t off = ((uint32_t)(kr * 128 + g * 16)) ^ swz;
                const bf16x8 kh = *(const bf16x8*)(kh_lds + off);
                const bf16x8 kl = *(const bf16x8*)(kl_lds + off);
                a = mfma16(kh, qh0, a);
                a = mfma16(kh, ql0, a);
                a = mfma16(kl, qh0, a);
            }
            {
                const uint32_t off = ((uint32_t)(kr * 128 + 64 + g * 16)) ^ swz;
                const bf16x8 kh = *(const bf16x8*)(kh_lds + off);
                const bf16x8 kl = *(const bf16x8*)(kl_lds + off);
                a = mfma16(kh, qh1, a);
                a = mfma16(kh, ql1, a);
                a = mfma16(kl, qh1, a);
            }
            sa[t] = a;
        }

        float tmax = sa[0][0];
        #pragma unroll
        for (int t = 0; t < 4; ++t)
            #pragma unroll
            for (int j = 0; j < 4; ++j) tmax = fmaxf(tmax, sa[t][j]);
        tmax = fmaxf(tmax, __shfl_xor(tmax, 16));
        tmax = fmaxf(tmax, __shfl_xor(tmax, 32));
        const float m_new = fmaxf(m_run, tmax);
        const float alpha = __builtin_amdgcn_exp2f(m_run - m_new);
        m_run = m_new;

        float lsum = 0.f;
        uint32_t pk[8];
        #pragma unroll
        for (int t = 0; t < 4; ++t) {
            const float p0 = __builtin_amdgcn_exp2f(sa[t][0] - m_new);
            const float p1 = __builtin_amdgcn_exp2f(sa[t][1] - m_new);
            const float p2 = __builtin_amdgcn_exp2f(sa[t][2] - m_new);
            const float p3 = __builtin_amdgcn_exp2f(sa[t][3] - m_new);
            lsum += (p0 + p1) + (p2 + p3);
            pk[2 * t]     = (uint32_t)f2bf(p0) | ((uint32_t)f2bf(p1) << 16);
            pk[2 * t + 1] = (uint32_t)f2bf(p2) | ((uint32_t)f2bf(p3) << 16);
        }
        lsum += __shfl_xor(lsum, 16);
        lsum += __shfl_xor(lsum, 32);
        l_run = l_run * alpha + lsum;

        #pragma unroll
        for (int t = 0; t < 4; ++t) {
            const uint32_t off = ((uint32_t)(lm * 128 + t * 32 + g * 8)) ^ pswz;
            uint2 val; val.x = pk[2 * t]; val.y = pk[2 * t + 1];
            *(uint2*)(pb + off) = val;
        }
        asm volatile("s_waitcnt lgkmcnt(0)" ::: "memory");
        __builtin_amdgcn_sched_barrier(0);

        const float av0 = __shfl(alpha, 4 * g + 0);
        const float av1 = __shfl(alpha, 4 * g + 1);
        const float av2 = __shfl(alpha, 4 * g + 2);
        const float av3 = __shfl(alpha, 4 * g + 3);
        const f32x4 am = {av0, av1, av2, av3};
        #pragma unroll
        for (int dt = 0; dt < 4; ++dt) O[dt] *= am;

        #pragma unroll
        for (int kc = 0; kc < 2; ++kc) {
            const uint32_t poff = ((uint32_t)(lm * 128 + kc * 64 + g * 16)) ^ pswz;
            const bf16x8 pa = *(const bf16x8*)(pb + poff);
            #pragma unroll
            for (int dt = 0; dt < 4; ++dt) {
                const int vr = dt * 16 + lm;
                const uint32_t voff = ((uint32_t)(vr * 128 + kc * 64 + g * 16)) ^ pswz;
                const bf16x8 vb = *(const bf16x8*)(vt_lds + voff);
                O[dt] = mfma16(pa, vb, O[dt]);
            }
        }
        __syncthreads();
    }

    const int b = bh >> 3, hh = bh & 7;
    #pragma unroll
    for (int j = 0; j < 4; ++j) {
        const float li = 1.f / __shfl(l_run, 4 * g + j);
        const int srow = qt * 64 + w * 16 + 4 * g + j;
        const size_t rbase = ((size_t)b * S_LEN + srow) * (NH * DOUT) + hh * DOUT;
        #pragma unroll
        for (int dt = 0; dt < 4; ++dt)
            oc[rbase + dt * 16 + lm] = f2bf(O[dt][j] * li);
    }
}

// ---------------------------------------------------------------------------
// Kernel 5: output projection out = o_concat[8192x512] @ wo[512x64], fp32 out.
// ---------------------------------------------------------------------------
__global__ __launch_bounds__(256) void oproj(
    const uint16_t* __restrict__ oc, const uint16_t* __restrict__ woT,
    float* __restrict__ out)
{
    const int mt = blockIdx.x;
    const int tid = threadIdx.x;
    const int l = tid & 63, w = tid >> 6;
    const int g = l >> 4, lm = l & 15;
    const int m0 = mt * 64 + w * 16;
    const f32x4 Z = {0.f, 0.f, 0.f, 0.f};
    f32x4 acc[4] = {Z, Z, Z, Z};
    const uint16_t* __restrict__ arow = oc + (size_t)(m0 + lm) * (NH * DOUT);
    for (int kc = 0; kc < 16; ++kc) {
        const bf16x8 a = *(const bf16x8*)(arow + kc * 32 + g * 8);
        #pragma unroll
        for (int nt = 0; nt < 4; ++nt) {
            const bf16x8 bfr = *(const bf16x8*)(woT + (size_t)(nt * 16 + lm) * (NH * DOUT) + kc * 32 + g * 8);
            acc[nt] = mfma16(a, bfr, acc[nt]);
        }
    }
    #pragma unroll
    for (int nt = 0; nt < 4; ++nt)
        #pragma unroll
        for (int j = 0; j < 4; ++j)
            out[(size_t)(m0 + 4 * g + j) * DOUT + nt * 16 + lm] = acc[nt][j];
}

// ---------------------------------------------------------------------------
extern "C" void kernel_launch(void* const* d_in, const int* in_sizes, int n_in,
                              void* d_out, int out_size, void* d_ws, size_t ws_size,
                              hipStream_t stream) {
    const float* x  = (const float*)d_in[0];
    const float* w  = (const float*)d_in[1];
    const float* wo = (const float*)d_in[2];
    float* out = (float*)d_out;

    char* ws = (char*)d_ws;
    uint16_t* qhi  = (uint16_t*)(ws);              // 8388608 B each
    uint16_t* qlo  = (uint16_t*)(ws + 8388608);
    uint16_t* khi  = (uint16_t*)(ws + 16777216);
    uint16_t* klo  = (uint16_t*)(ws + 25165824);
    uint16_t* vbf  = (uint16_t*)(ws + 33554432);
    uint16_t* xhi  = (uint16_t*)(ws + 41943040);   // 8388608 B
    uint16_t* xlo  = (uint16_t*)(ws + 50331648);   // 8388608 B
    uint16_t* whiT = (uint16_t*)(ws + 58720256);   // [1536][512] bf16, 1572864 B
    uint16_t* wloT = (uint16_t*)(ws + 60293120);
    uint16_t* woT  = (uint16_t*)(ws + 61865984);   // 65536 B
    // oc aliases xhi: attn writes it only after gemm_qkv has consumed xhi;
    // split_x rewrites xhi every call before gemm_qkv reads it.
    uint16_t* oc   = xhi;
    // total: 61931520 B (~59 MB)

    hipLaunchKernelGGL(prep_w, dim3(200), dim3(256), 0, stream, w, wo, whiT, wloT, woT);
    hipLaunchKernelGGL(split_x, dim3(2048), dim3(256), 0, stream, x, xhi, xlo);
    hipLaunchKernelGGL(gemm_qkv, dim3(768), dim3(256), 0, stream,
                       xhi, xlo, whiT, wloT, qhi, qlo, khi, klo, vbf);
    hipLaunchKernelGGL(attn_fwd, dim3(32, 32), dim3(256), 0, stream,
                       qhi, qlo, khi, klo, vbf, oc);
    hipLaunchKernelGGL(oproj, dim3(128), dim3(256), 0, stream, oc, woT, out);
}

// Round 3
// 201.108 us; speedup vs baseline: 1.8829x; 1.0298x over previous
//
#include <hip/hip_runtime.h>
#include <cstdint>
#include <cstddef>

#define S_LEN 2048
#define DIN   512
#define DOUT  64
#define NB    4
#define NH    8

typedef __attribute__((ext_vector_type(8))) short bf16x8;
typedef __attribute__((ext_vector_type(4))) float f32x4;

static __device__ __forceinline__ f32x4 mfma16(bf16x8 a, bf16x8 b, f32x4 c) {
    return __builtin_amdgcn_mfma_f32_16x16x32_bf16(a, b, c, 0, 0, 0);
}

static __device__ __forceinline__ uint16_t f2bf(float x) {
    uint32_t u = __builtin_bit_cast(uint32_t, x);
    u += 0x7fffu + ((u >> 16) & 1u);
    return (uint16_t)(u >> 16);
}
static __device__ __forceinline__ float bf2f(uint16_t h) {
    uint32_t u = ((uint32_t)h) << 16;
    return __builtin_bit_cast(float, u);
}

typedef const __attribute__((address_space(1))) void* as1p;
typedef __attribute__((address_space(3))) void* as3p;
static __device__ __forceinline__ void gload_lds16(const void* g, void* l) {
    __builtin_amdgcn_global_load_lds((as1p)g, (as3p)l, 16, 0, 0);
}

// ---------------------------------------------------------------------------
// Kernel 1: weight prep via LDS transpose (coalesced both sides).
// ---------------------------------------------------------------------------
__global__ __launch_bounds__(256) void prep_w(
    const float* __restrict__ w, const float* __restrict__ wo,
    uint16_t* __restrict__ whiT, uint16_t* __restrict__ wloT,
    uint16_t* __restrict__ woT)
{
    __shared__ float tile[64][65];
    const int blk = blockIdx.x;
    const int t = threadIdx.x;
    const int tq = t >> 6, tr = t & 63;

    if (blk < 192) {
        const int hp = blk >> 3, i0 = (blk & 7) * 64;
        const int p = hp % 3;
        const float s = (p == 0) ? 0.18033688011112042f : 1.0f; // 0.125*log2(e)
        const float* __restrict__ src = w + (size_t)hp * (DIN * DOUT);
        #pragma unroll
        for (int r = 0; r < 16; ++r) {
            const int ir = r * 4 + tq;
            tile[ir][tr] = src[(size_t)(i0 + ir) * DOUT + tr];
        }
        __syncthreads();
        uint16_t* __restrict__ dh = whiT + (size_t)hp * (DOUT * DIN);
        uint16_t* __restrict__ dl = wloT + (size_t)hp * (DOUT * DIN);
        #pragma unroll
        for (int r = 0; r < 16; ++r) {
            const int o = r * 4 + tq;
            const float v = tile[tr][o] * s;
            const uint16_t hi = f2bf(v);
            dh[(size_t)o * DIN + i0 + tr] = hi;
            dl[(size_t)o * DIN + i0 + tr] = f2bf(v - bf2f(hi));
        }
    } else {
        const int i0 = (blk - 192) * 64;
        #pragma unroll
        for (int r = 0; r < 16; ++r) {
            const int ir = r * 4 + tq;
            tile[ir][tr] = wo[(size_t)(i0 + ir) * DOUT + tr];
        }
        __syncthreads();
        #pragma unroll
        for (int r = 0; r < 16; ++r) {
            const int o = r * 4 + tq;
            woT[(size_t)o * DIN + i0 + tr] = f2bf(tile[tr][o]);
        }
    }
}

// ---------------------------------------------------------------------------
// Kernel 2: split x [8192][512] fp32 -> xhi/xlo bf16 (vectorized, one pass).
// ---------------------------------------------------------------------------
__global__ __launch_bounds__(256) void split_x(
    const float* __restrict__ x, uint16_t* __restrict__ xhi, uint16_t* __restrict__ xlo)
{
    const size_t idx = ((size_t)blockIdx.x * 256 + threadIdx.x) * 8;
    const float4 a = *(const float4*)(x + idx);
    const float4 b = *(const float4*)(x + idx + 4);
    const float xv[8] = {a.x, a.y, a.z, a.w, b.x, b.y, b.z, b.w};
    union { uint16_t u[8]; uint4 v; } H, L;
    #pragma unroll
    for (int j = 0; j < 8; ++j) {
        const uint16_t hi = f2bf(xv[j]);
        H.u[j] = hi;
        L.u[j] = f2bf(xv[j] - bf2f(hi));
    }
    *(uint4*)(xhi + idx) = H.v;
    *(uint4*)(xlo + idx) = L.v;
}

// ---------------------------------------------------------------------------
// Kernel 3: QKV projection GEMM (unchanged from R2, m97 structure).
// ---------------------------------------------------------------------------
__global__ __launch_bounds__(256) void gemm_qkv(
    const uint16_t* __restrict__ xhi, const uint16_t* __restrict__ xlo,
    const uint16_t* __restrict__ whiT, const uint16_t* __restrict__ wloT,
    uint16_t* __restrict__ qhi, uint16_t* __restrict__ qlo,
    uint16_t* __restrict__ khi, uint16_t* __restrict__ klo,
    uint16_t* __restrict__ vbf)
{
    __shared__ __align__(16) uint16_t lds[2 * 128 * 64];

    const int bid = blockIdx.x;
    const int xcd = bid & 7, wi = bid >> 3;
    const int mt = xcd * 8 + wi / 12, nt = wi % 12;
    const int m0 = mt * 128, n0 = nt * 128;
    const int tid = threadIdx.x;
    const int l = tid & 63, w = tid >> 6;
    const int g = l >> 4, lm = l & 15;
    const int wm = w >> 1, wn = w & 1;

    const f32x4 Z = {0.f, 0.f, 0.f, 0.f};
    f32x4 acc[4][4];
    #pragma unroll
    for (int a = 0; a < 4; ++a)
        #pragma unroll
        for (int b = 0; b < 4; ++b) acc[a][b] = Z;

    int srow[4], scol[4];
    #pragma unroll
    for (int i = 0; i < 4; ++i) {
        const int c = i * 256 + tid;
        srow[i] = c >> 3;
        scol[i] = ((c & 7) * 8) ^ ((srow[i] & 7) << 3);
    }

    for (int kt = 0; kt < 24; ++kt) {
        const int k0 = (kt & 7) * 64;
        const uint16_t* __restrict__ As = (kt < 16) ? xhi : xlo;
        const uint16_t* __restrict__ Bs = (kt >= 8 && kt < 16) ? wloT : whiT;
        #pragma unroll
        for (int i = 0; i < 4; ++i) {
            const int c8 = (i * 256 + tid) * 8;
            gload_lds16(As + (size_t)(m0 + srow[i]) * DIN + k0 + scol[i], &lds[c8]);
            gload_lds16(Bs + (size_t)(n0 + srow[i]) * DIN + k0 + scol[i], &lds[128 * 64 + c8]);
        }
        asm volatile("s_waitcnt vmcnt(0)" ::: "memory");
        __syncthreads();

        bf16x8 af[4][2];
        #pragma unroll
        for (int mi = 0; mi < 4; ++mi) {
            const int r = wm * 64 + mi * 16 + lm;
            const int rb = r * 128;
            #pragma unroll
            for (int kk = 0; kk < 2; ++kk) {
                const int cb = (kk * 64 + g * 16) ^ ((r & 7) << 4);
                af[mi][kk] = *(const bf16x8*)((const char*)lds + rb + cb);
            }
        }
        #pragma unroll
        for (int ni = 0; ni < 4; ++ni) {
            const int r = wn * 64 + ni * 16 + lm;
            const int rb = 128 * 64 * 2 + r * 128;
            bf16x8 bfr[2];
            #pragma unroll
            for (int kk = 0; kk < 2; ++kk) {
                const int cb = (kk * 64 + g * 16) ^ ((r & 7) << 4);
                bfr[kk] = *(const bf16x8*)((const char*)lds + rb + cb);
            }
            #pragma unroll
            for (int mi = 0; mi < 4; ++mi) {
                acc[mi][ni] = mfma16(af[mi][0], bfr[0], acc[mi][ni]);
                acc[mi][ni] = mfma16(af[mi][1], bfr[1], acc[mi][ni]);
            }
        }
        __syncthreads();
    }

    #pragma unroll
    for (int ni = 0; ni < 4; ++ni) {
        const int n = n0 + wn * 64 + ni * 16 + lm;
        const int hp = n >> 6, o = n & 63;
        const int h = hp / 3, p = hp - h * 3;
        uint16_t* __restrict__ dhi = (p == 0) ? qhi : khi;
        uint16_t* __restrict__ dlo = (p == 0) ? qlo : klo;
        #pragma unroll
        for (int mi = 0; mi < 4; ++mi) {
            #pragma unroll
            for (int j = 0; j < 4; ++j) {
                const int m = m0 + wm * 64 + mi * 16 + 4 * g + j;
                const int b = m >> 11, s = m & 2047;
                const size_t idx = ((size_t)(b * NH + h) * S_LEN + s) * DOUT + o;
                const float v = acc[mi][ni][j];
                if (p < 2) {
                    const uint16_t hi = f2bf(v);
                    dhi[idx] = hi;
                    dlo[idx] = f2bf(v - bf2f(hi));
                } else {
                    vbf[idx] = f2bf(v);
                }
            }
        }
    }
}

// ---------------------------------------------------------------------------
// Kernel 4: V transpose [bh][2048][64] -> vT [bh][64][2048] (LDS-tiled).
// ---------------------------------------------------------------------------
__global__ __launch_bounds__(256) void transpose_v(
    const uint16_t* __restrict__ vbf, uint16_t* __restrict__ vT)
{
    __shared__ __align__(16) uint16_t t[64][72];
    const int st = blockIdx.x, bh = blockIdx.y;
    const int tid = threadIdx.x;
    const size_t base = (size_t)bh * (S_LEN * DOUT);
    #pragma unroll
    for (int i = 0; i < 2; ++i) {
        const int c = tid + 256 * i, r = c >> 3, sl = c & 7;
        const uint4 vv = *(const uint4*)(vbf + base + (size_t)(st * 64 + r) * DOUT + sl * 8);
        *(uint4*)&t[r][sl * 8] = vv;
    }
    __syncthreads();
    #pragma unroll
    for (int i = 0; i < 2; ++i) {
        const int c = tid + 256 * i, d = c >> 3, sl = c & 7;
        uint16_t tmp[8];
        #pragma unroll
        for (int jj = 0; jj < 8; ++jj) tmp[jj] = t[sl * 8 + jj][d];
        *(uint4*)(vT + base + (size_t)d * S_LEN + st * 64 + sl * 8) = *(uint4*)tmp;
    }
}

// ---------------------------------------------------------------------------
// Kernel 5: flash attention, pipelined.
//   grid 1024: xcd-aware decode (bh == xcd mod 8 -> per-XCD L2 holds 4 heads).
//   LDS 48KB: K(hi+lo) double-buffered (2x16KB) + V single (8KB) + P (8KB).
//   Per iter: issue V(kt)+K(kt+1) DMA -> QK+softmax (overlaps loads) ->
//   vmcnt(4) (V landed, K in flight) + raw barrier -> PV -> vmcnt(0)+barrier.
// ---------------------------------------------------------------------------
__global__ __launch_bounds__(256) void attn_fwd(
    const uint16_t* __restrict__ qhi, const uint16_t* __restrict__ qlo,
    const uint16_t* __restrict__ khi, const uint16_t* __restrict__ klo,
    const uint16_t* __restrict__ vT, uint16_t* __restrict__ oc)
{
    __shared__ __align__(16) char smem[49152];
    // [0,16384): kbuf0 (khi 8KB | klo 8KB)  [16384,32768): kbuf1
    // [32768,40960): vbuf   [40960,49152): p_lds (4 waves x 2KB)
    char* __restrict__ vbuf  = smem + 32768;
    char* __restrict__ p_lds = smem + 40960;

    const int bid = blockIdx.x;
    const int qt = (bid >> 3) & 31, bh = (bid >> 8) * 8 + (bid & 7);
    const int tid = threadIdx.x;
    const int l = tid & 63, w = tid >> 6;
    const int g = l >> 4, lm = l & 15;
    const size_t base  = (size_t)bh * (S_LEN * DOUT);
    const size_t vbase = (size_t)bh * (DOUT * S_LEN);

    // staging chunks: c = tid + 256*i -> LDS byte c*16; row=c>>3, slot=c&7,
    // source col elems = (slot*8) ^ ((row&7)<<3)   (inverse of read swizzle)
    const int c0 = tid, c1 = tid + 256;
    const int r0 = c0 >> 3, sc0 = ((c0 & 7) * 8) ^ ((r0 & 7) << 3);
    const int r1 = c1 >> 3, sc1 = ((c1 & 7) * 8) ^ ((r1 & 7) << 3);

    // Q fragments: lane holds Q[q=lm][d = 32c + 8g + j]
    const int qrow = qt * 64 + w * 16 + lm;
    const uint16_t* qp  = qhi + base + (size_t)qrow * DOUT;
    const uint16_t* qlp = qlo + base + (size_t)qrow * DOUT;
    const bf16x8 qh0 = *(const bf16x8*)(qp + g * 8);
    const bf16x8 qh1 = *(const bf16x8*)(qp + 32 + g * 8);
    const bf16x8 ql0 = *(const bf16x8*)(qlp + g * 8);
    const bf16x8 ql1 = *(const bf16x8*)(qlp + 32 + g * 8);

    const f32x4 Z = {0.f, 0.f, 0.f, 0.f};
    f32x4 O[4] = {Z, Z, Z, Z};
    float m_run = -INFINITY, l_run = 0.f;

    char* __restrict__ pb = p_lds + w * 2048;
    const uint32_t pswz = (uint32_t)((lm & 7) << 4);

    // prologue: stage K(0) into kbuf0
    gload_lds16(khi + base + (size_t)r0 * DOUT + sc0, smem + c0 * 16);
    gload_lds16(khi + base + (size_t)r1 * DOUT + sc1, smem + c1 * 16);
    gload_lds16(klo + base + (size_t)r0 * DOUT + sc0, smem + 8192 + c0 * 16);
    gload_lds16(klo + base + (size_t)r1 * DOUT + sc1, smem + 8192 + c1 * 16);
    asm volatile("s_waitcnt vmcnt(0)" ::: "memory");
    __builtin_amdgcn_s_barrier();
    __builtin_amdgcn_sched_barrier(0);

    for (int kt = 0; kt < 32; ++kt) {
        const int cur = kt & 1;
        char* __restrict__ kb = smem + cur * 16384;
        const int s0 = kt * 64;

        // [A] stage V(kt) (oldest) then K(kt+1) (dummy tile 0 on last iter
        //     to keep vmcnt counts uniform)
        gload_lds16(vT + vbase + (size_t)r0 * S_LEN + s0 + sc0, vbuf + c0 * 16);
        gload_lds16(vT + vbase + (size_t)r1 * S_LEN + s0 + sc1, vbuf + c1 * 16);
        {
            char* __restrict__ kn = smem + (cur ^ 1) * 16384;
            const int sn = (kt < 31) ? s0 + 64 : 0;
            gload_lds16(khi + base + (size_t)(sn + r0) * DOUT + sc0, kn + c0 * 16);
            gload_lds16(khi + base + (size_t)(sn + r1) * DOUT + sc1, kn + c1 * 16);
            gload_lds16(klo + base + (size_t)(sn + r0) * DOUT + sc0, kn + 8192 + c0 * 16);
            gload_lds16(klo + base + (size_t)(sn + r1) * DOUT + sc1, kn + 8192 + c1 * 16);
        }

        // [B] QK^T (swapped): lane has q=lm, k = 16t + 4g + j
        char* __restrict__ khb = kb;
        char* __restrict__ klb = kb + 8192;
        f32x4 sa[4];
        __builtin_amdgcn_s_setprio(1);
        #pragma unroll
        for (int t = 0; t < 4; ++t) {
            f32x4 a = Z;
            const int kr = t * 16 + lm;
            const uint32_t swz = (uint32_t)((kr & 7) << 4);
            {
                const uint32_t off = ((uint32_t)(kr * 128 + g * 16)) ^ swz;
                const bf16x8 kh = *(const bf16x8*)(khb + off);
                const bf16x8 kl = *(const bf16x8*)(klb + off);
                a = mfma16(kh, qh0, a);
                a = mfma16(kh, ql0, a);
                a = mfma16(kl, qh0, a);
            }
            {
                const uint32_t off = ((uint32_t)(kr * 128 + 64 + g * 16)) ^ swz;
                const bf16x8 kh = *(const bf16x8*)(khb + off);
                const bf16x8 kl = *(const bf16x8*)(klb + off);
                a = mfma16(kh, qh1, a);
                a = mfma16(kh, ql1, a);
                a = mfma16(kl, qh1, a);
            }
            sa[t] = a;
        }
        __builtin_amdgcn_s_setprio(0);

        // online softmax (exp2-domain)
        float tmax = sa[0][0];
        #pragma unroll
        for (int t = 0; t < 4; ++t)
            #pragma unroll
            for (int j = 0; j < 4; ++j) tmax = fmaxf(tmax, sa[t][j]);
        tmax = fmaxf(tmax, __shfl_xor(tmax, 16));
        tmax = fmaxf(tmax, __shfl_xor(tmax, 32));
        const float m_new = fmaxf(m_run, tmax);
        const float alpha = __builtin_amdgcn_exp2f(m_run - m_new);
        m_run = m_new;

        float lsum = 0.f;
        uint32_t pk[8];
        #pragma unroll
        for (int t = 0; t < 4; ++t) {
            const float p0 = __builtin_amdgcn_exp2f(sa[t][0] - m_new);
            const float p1 = __builtin_amdgcn_exp2f(sa[t][1] - m_new);
            const float p2 = __builtin_amdgcn_exp2f(sa[t][2] - m_new);
            const float p3 = __builtin_amdgcn_exp2f(sa[t][3] - m_new);
            lsum += (p0 + p1) + (p2 + p3);
            pk[2 * t]     = (uint32_t)f2bf(p0) | ((uint32_t)f2bf(p1) << 16);
            pk[2 * t + 1] = (uint32_t)f2bf(p2) | ((uint32_t)f2bf(p3) << 16);
        }
        lsum += __shfl_xor(lsum, 16);
        lsum += __shfl_xor(lsum, 32);
        l_run = l_run * alpha + lsum;

        // P -> wave-private LDS [q][k] bf16
        #pragma unroll
        for (int t = 0; t < 4; ++t) {
            const uint32_t off = ((uint32_t)(lm * 128 + t * 32 + g * 8)) ^ pswz;
            uint2 val; val.x = pk[2 * t]; val.y = pk[2 * t + 1];
            *(uint2*)(pb + off) = val;
        }

        // rescale O by alpha (per O-row q = 4g + j)
        const float av0 = __shfl(alpha, 4 * g + 0);
        const float av1 = __shfl(alpha, 4 * g + 1);
        const float av2 = __shfl(alpha, 4 * g + 2);
        const float av3 = __shfl(alpha, 4 * g + 3);
        const f32x4 am = {av0, av1, av2, av3};
        #pragma unroll
        for (int dt = 0; dt < 4; ++dt) O[dt] *= am;

        // [C] V landed (own 2 oldest); K(kt+1) still in flight
        asm volatile("s_waitcnt vmcnt(4) lgkmcnt(0)" ::: "memory");
        __builtin_amdgcn_s_barrier();
        __builtin_amdgcn_sched_barrier(0);

        // [D] PV: O[16q x 64d] += P[16q x 64k] * V^T rows
        __builtin_amdgcn_s_setprio(1);
        #pragma unroll
        for (int kc = 0; kc < 2; ++kc) {
            const uint32_t poff = ((uint32_t)(lm * 128 + kc * 64 + g * 16)) ^ pswz;
            const bf16x8 pa = *(const bf16x8*)(pb + poff);
            #pragma unroll
            for (int dt = 0; dt < 4; ++dt) {
                const int vr = dt * 16 + lm;
                const uint32_t voff = (uint32_t)(vr * 128 + ((kc * 64 + g * 16) ^ ((vr & 7) << 4)));
                const bf16x8 vb = *(const bf16x8*)(vbuf + voff);
                O[dt] = mfma16(pa, vb, O[dt]);
            }
        }
        __builtin_amdgcn_s_setprio(0);

        // [E] K(kt+1) resident; all waves done with vbuf/kbuf reads
        asm volatile("s_waitcnt vmcnt(0)" ::: "memory");
        __builtin_amdgcn_s_barrier();
        __builtin_amdgcn_sched_barrier(0);
    }

    // epilogue: normalize, write o_concat[b][s][h*64+d] bf16
    const int b = bh >> 3, hh = bh & 7;
    #pragma unroll
    for (int j = 0; j < 4; ++j) {
        const float li = 1.f / __shfl(l_run, 4 * g + j);
        const int srow = qt * 64 + w * 16 + 4 * g + j;
        const size_t rbase = ((size_t)b * S_LEN + srow) * (NH * DOUT) + hh * DOUT;
        #pragma unroll
        for (int dt = 0; dt < 4; ++dt)
            oc[rbase + dt * 16 + lm] = f2bf(O[dt][j] * li);
    }
}

// ---------------------------------------------------------------------------
// Kernel 6: output projection out = o_concat[8192x512] @ wo[512x64], fp32 out.
// ---------------------------------------------------------------------------
__global__ __launch_bounds__(256) void oproj(
    const uint16_t* __restrict__ oc, const uint16_t* __restrict__ woT,
    float* __restrict__ out)
{
    const int mt = blockIdx.x;
    const int tid = threadIdx.x;
    const int l = tid & 63, w = tid >> 6;
    const int g = l >> 4, lm = l & 15;
    const int m0 = mt * 64 + w * 16;
    const f32x4 Z = {0.f, 0.f, 0.f, 0.f};
    f32x4 acc[4] = {Z, Z, Z, Z};
    const uint16_t* __restrict__ arow = oc + (size_t)(m0 + lm) * (NH * DOUT);
    for (int kc = 0; kc < 16; ++kc) {
        const bf16x8 a = *(const bf16x8*)(arow + kc * 32 + g * 8);
        #pragma unroll
        for (int nt = 0; nt < 4; ++nt) {
            const bf16x8 bfr = *(const bf16x8*)(woT + (size_t)(nt * 16 + lm) * (NH * DOUT) + kc * 32 + g * 8);
            acc[nt] = mfma16(a, bfr, acc[nt]);
        }
    }
    #pragma unroll
    for (int nt = 0; nt < 4; ++nt)
        #pragma unroll
        for (int j = 0; j < 4; ++j)
            out[(size_t)(m0 + 4 * g + j) * DOUT + nt * 16 + lm] = acc[nt][j];
}

// ---------------------------------------------------------------------------
extern "C" void kernel_launch(void* const* d_in, const int* in_sizes, int n_in,
                              void* d_out, int out_size, void* d_ws, size_t ws_size,
                              hipStream_t stream) {
    const float* x  = (const float*)d_in[0];
    const float* w  = (const float*)d_in[1];
    const float* wo = (const float*)d_in[2];
    float* out = (float*)d_out;

    char* ws = (char*)d_ws;
    uint16_t* qhi  = (uint16_t*)(ws);              // 8388608 B each
    uint16_t* qlo  = (uint16_t*)(ws + 8388608);
    uint16_t* khi  = (uint16_t*)(ws + 16777216);
    uint16_t* klo  = (uint16_t*)(ws + 25165824);
    uint16_t* vbf  = (uint16_t*)(ws + 33554432);
    uint16_t* xhi  = (uint16_t*)(ws + 41943040);   // 8388608 B
    uint16_t* xlo  = (uint16_t*)(ws + 50331648);   // 8388608 B
    uint16_t* whiT = (uint16_t*)(ws + 58720256);   // 1572864 B
    uint16_t* wloT = (uint16_t*)(ws + 60293120);
    uint16_t* woT  = (uint16_t*)(ws + 61865984);   // 65536 B
    // aliases: oc over xhi (xhi dead after gemm_qkv); vT over xlo (dead after
    // gemm_qkv). split_x rewrites xhi/xlo every call before gemm_qkv reads them.
    uint16_t* oc   = xhi;
    uint16_t* vT   = xlo;
    // total: 61931520 B (~59 MB)

    hipLaunchKernelGGL(prep_w, dim3(200), dim3(256), 0, stream, w, wo, whiT, wloT, woT);
    hipLaunchKernelGGL(split_x, dim3(2048), dim3(256), 0, stream, x, xhi, xlo);
    hipLaunchKernelGGL(gemm_qkv, dim3(768), dim3(256), 0, stream,
                       xhi, xlo, whiT, wloT, qhi, qlo, khi, klo, vbf);
    hipLaunchKernelGGL(transpose_v, dim3(32, 32), dim3(256), 0, stream, vbf, vT);
    hipLaunchKernelGGL(attn_fwd, dim3(1024), dim3(256), 0, stream,
                       qhi, qlo, khi, klo, vT, oc);
    hipLaunchKernelGGL(oproj, dim3(128), dim3(256), 0, stream, oc, woT, out);
}

// Round 4
// 170.916 us; speedup vs baseline: 2.2155x; 1.1766x over previous
//
#include <hip/hip_runtime.h>
#include <cstdint>
#include <cstddef>

#define S_LEN 2048
#define DIN   512
#define DOUT  64
#define NB    4
#define NH    8

typedef __attribute__((ext_vector_type(8))) short bf16x8;
typedef __attribute__((ext_vector_type(4))) float f32x4;

static __device__ __forceinline__ f32x4 mfma16(bf16x8 a, bf16x8 b, f32x4 c) {
    return __builtin_amdgcn_mfma_f32_16x16x32_bf16(a, b, c, 0, 0, 0);
}

static __device__ __forceinline__ uint16_t f2bf(float x) {
    uint32_t u = __builtin_bit_cast(uint32_t, x);
    u += 0x7fffu + ((u >> 16) & 1u);
    return (uint16_t)(u >> 16);
}
static __device__ __forceinline__ float bf2f(uint16_t h) {
    uint32_t u = ((uint32_t)h) << 16;
    return __builtin_bit_cast(float, u);
}
static __device__ __forceinline__ uint32_t cvt_pk_bf16(float lo, float hi) {
    uint32_t r;
    asm("v_cvt_pk_bf16_f32 %0, %1, %2" : "=v"(r) : "v"(lo), "v"(hi));
    return r;
}

typedef const __attribute__((address_space(1))) void* as1p;
typedef __attribute__((address_space(3))) void* as3p;
static __device__ __forceinline__ void gload_lds16(const void* g, void* l) {
    __builtin_amdgcn_global_load_lds((as1p)g, (as3p)l, 16, 0, 0);
}

// ---------------------------------------------------------------------------
// Kernel 1: weight prep via LDS transpose (coalesced both sides).
// ---------------------------------------------------------------------------
__global__ __launch_bounds__(256) void prep_w(
    const float* __restrict__ w, const float* __restrict__ wo,
    uint16_t* __restrict__ whiT, uint16_t* __restrict__ wloT,
    uint16_t* __restrict__ woT)
{
    __shared__ float tile[64][65];
    const int blk = blockIdx.x;
    const int t = threadIdx.x;
    const int tq = t >> 6, tr = t & 63;

    if (blk < 192) {
        const int hp = blk >> 3, i0 = (blk & 7) * 64;
        const int p = hp % 3;
        const float s = (p == 0) ? 0.18033688011112042f : 1.0f; // 0.125*log2(e)
        const float* __restrict__ src = w + (size_t)hp * (DIN * DOUT);
        #pragma unroll
        for (int r = 0; r < 16; ++r) {
            const int ir = r * 4 + tq;
            tile[ir][tr] = src[(size_t)(i0 + ir) * DOUT + tr];
        }
        __syncthreads();
        uint16_t* __restrict__ dh = whiT + (size_t)hp * (DOUT * DIN);
        uint16_t* __restrict__ dl = wloT + (size_t)hp * (DOUT * DIN);
        #pragma unroll
        for (int r = 0; r < 16; ++r) {
            const int o = r * 4 + tq;
            const float v = tile[tr][o] * s;
            const uint16_t hi = f2bf(v);
            dh[(size_t)o * DIN + i0 + tr] = hi;
            dl[(size_t)o * DIN + i0 + tr] = f2bf(v - bf2f(hi));
        }
    } else {
        const int i0 = (blk - 192) * 64;
        #pragma unroll
        for (int r = 0; r < 16; ++r) {
            const int ir = r * 4 + tq;
            tile[ir][tr] = wo[(size_t)(i0 + ir) * DOUT + tr];
        }
        __syncthreads();
        #pragma unroll
        for (int r = 0; r < 16; ++r) {
            const int o = r * 4 + tq;
            woT[(size_t)o * DIN + i0 + tr] = f2bf(tile[tr][o]);
        }
    }
}

// ---------------------------------------------------------------------------
// Kernel 2: split x [8192][512] fp32 -> xhi/xlo bf16 (vectorized, one pass).
// ---------------------------------------------------------------------------
__global__ __launch_bounds__(256) void split_x(
    const float* __restrict__ x, uint16_t* __restrict__ xhi, uint16_t* __restrict__ xlo)
{
    const size_t idx = ((size_t)blockIdx.x * 256 + threadIdx.x) * 8;
    const float4 a = *(const float4*)(x + idx);
    const float4 b = *(const float4*)(x + idx + 4);
    const float xv[8] = {a.x, a.y, a.z, a.w, b.x, b.y, b.z, b.w};
    union { uint16_t u[8]; uint4 v; } H, L;
    #pragma unroll
    for (int j = 0; j < 8; ++j) {
        const uint16_t hi = f2bf(xv[j]);
        H.u[j] = hi;
        L.u[j] = f2bf(xv[j] - bf2f(hi));
    }
    *(uint4*)(xhi + idx) = H.v;
    *(uint4*)(xlo + idx) = L.v;
}

// ---------------------------------------------------------------------------
// Kernel 3: QKV projection GEMM (m97 structure, unchanged).
// ---------------------------------------------------------------------------
__global__ __launch_bounds__(256) void gemm_qkv(
    const uint16_t* __restrict__ xhi, const uint16_t* __restrict__ xlo,
    const uint16_t* __restrict__ whiT, const uint16_t* __restrict__ wloT,
    uint16_t* __restrict__ qhi, uint16_t* __restrict__ qlo,
    uint16_t* __restrict__ khi, uint16_t* __restrict__ klo,
    uint16_t* __restrict__ vbf)
{
    __shared__ __align__(16) uint16_t lds[2 * 128 * 64];

    const int bid = blockIdx.x;
    const int xcd = bid & 7, wi = bid >> 3;
    const int mt = xcd * 8 + wi / 12, nt = wi % 12;
    const int m0 = mt * 128, n0 = nt * 128;
    const int tid = threadIdx.x;
    const int l = tid & 63, w = tid >> 6;
    const int g = l >> 4, lm = l & 15;
    const int wm = w >> 1, wn = w & 1;

    const f32x4 Z = {0.f, 0.f, 0.f, 0.f};
    f32x4 acc[4][4];
    #pragma unroll
    for (int a = 0; a < 4; ++a)
        #pragma unroll
        for (int b = 0; b < 4; ++b) acc[a][b] = Z;

    int srow[4], scol[4];
    #pragma unroll
    for (int i = 0; i < 4; ++i) {
        const int c = i * 256 + tid;
        srow[i] = c >> 3;
        scol[i] = ((c & 7) * 8) ^ ((srow[i] & 7) << 3);
    }

    for (int kt = 0; kt < 24; ++kt) {
        const int k0 = (kt & 7) * 64;
        const uint16_t* __restrict__ As = (kt < 16) ? xhi : xlo;
        const uint16_t* __restrict__ Bs = (kt >= 8 && kt < 16) ? wloT : whiT;
        #pragma unroll
        for (int i = 0; i < 4; ++i) {
            const int c8 = (i * 256 + tid) * 8;
            gload_lds16(As + (size_t)(m0 + srow[i]) * DIN + k0 + scol[i], &lds[c8]);
            gload_lds16(Bs + (size_t)(n0 + srow[i]) * DIN + k0 + scol[i], &lds[128 * 64 + c8]);
        }
        asm volatile("s_waitcnt vmcnt(0)" ::: "memory");
        __syncthreads();

        bf16x8 af[4][2];
        #pragma unroll
        for (int mi = 0; mi < 4; ++mi) {
            const int r = wm * 64 + mi * 16 + lm;
            const int rb = r * 128;
            #pragma unroll
            for (int kk = 0; kk < 2; ++kk) {
                const int cb = (kk * 64 + g * 16) ^ ((r & 7) << 4);
                af[mi][kk] = *(const bf16x8*)((const char*)lds + rb + cb);
            }
        }
        #pragma unroll
        for (int ni = 0; ni < 4; ++ni) {
            const int r = wn * 64 + ni * 16 + lm;
            const int rb = 128 * 64 * 2 + r * 128;
            bf16x8 bfr[2];
            #pragma unroll
            for (int kk = 0; kk < 2; ++kk) {
                const int cb = (kk * 64 + g * 16) ^ ((r & 7) << 4);
                bfr[kk] = *(const bf16x8*)((const char*)lds + rb + cb);
            }
            #pragma unroll
            for (int mi = 0; mi < 4; ++mi) {
                acc[mi][ni] = mfma16(af[mi][0], bfr[0], acc[mi][ni]);
                acc[mi][ni] = mfma16(af[mi][1], bfr[1], acc[mi][ni]);
            }
        }
        __syncthreads();
    }

    #pragma unroll
    for (int ni = 0; ni < 4; ++ni) {
        const int n = n0 + wn * 64 + ni * 16 + lm;
        const int hp = n >> 6, o = n & 63;
        const int h = hp / 3, p = hp - h * 3;
        uint16_t* __restrict__ dhi = (p == 0) ? qhi : khi;
        uint16_t* __restrict__ dlo = (p == 0) ? qlo : klo;
        #pragma unroll
        for (int mi = 0; mi < 4; ++mi) {
            #pragma unroll
            for (int j = 0; j < 4; ++j) {
                const int m = m0 + wm * 64 + mi * 16 + 4 * g + j;
                const int b = m >> 11, s = m & 2047;
                const size_t idx = ((size_t)(b * NH + h) * S_LEN + s) * DOUT + o;
                const float v = acc[mi][ni][j];
                if (p < 2) {
                    const uint16_t hi = f2bf(v);
                    dhi[idx] = hi;
                    dlo[idx] = f2bf(v - bf2f(hi));
                } else {
                    vbf[idx] = f2bf(v);
                }
            }
        }
    }
}

// ---------------------------------------------------------------------------
// Kernel 4: V transpose [bh][2048][64] -> vT [bh][64][2048] (LDS-tiled).
// ---------------------------------------------------------------------------
__global__ __launch_bounds__(256) void transpose_v(
    const uint16_t* __restrict__ vbf, uint16_t* __restrict__ vT)
{
    __shared__ __align__(16) uint16_t t[64][72];
    const int st = blockIdx.x, bh = blockIdx.y;
    const int tid = threadIdx.x;
    const size_t base = (size_t)bh * (S_LEN * DOUT);
    #pragma unroll
    for (int i = 0; i < 2; ++i) {
        const int c = tid + 256 * i, r = c >> 3, sl = c & 7;
        const uint4 vv = *(const uint4*)(vbf + base + (size_t)(st * 64 + r) * DOUT + sl * 8);
        *(uint4*)&t[r][sl * 8] = vv;
    }
    __syncthreads();
    #pragma unroll
    for (int i = 0; i < 2; ++i) {
        const int c = tid + 256 * i, d = c >> 3, sl = c & 7;
        uint16_t tmp[8];
        #pragma unroll
        for (int jj = 0; jj < 8; ++jj) tmp[jj] = t[sl * 8 + jj][d];
        *(uint4*)(vT + base + (size_t)d * S_LEN + st * 64 + sl * 8) = *(uint4*)tmp;
    }
}

// ---------------------------------------------------------------------------
// Kernel 5: flash attention, 8 waves / 512 threads, QBLK=128, no-drain pipe.
//   grid 512: bh = (bid&7) + 8*(bid>>7) -> 4 heads per XCD L2.
//   LDS 56KB: kbuf0/1 (16KB each: khi|klo) + vbuf 8KB + P 16KB -> 2 blk/CU.
//   Schedule: [A] issue V(kt),K(kt+1) -> vmcnt(3)+bar (K(kt) landed) ->
//   [B] QK+softmax (cvt_pk, defer-max) -> vmcnt(2)+bar (V landed; K in
//   flight) -> [D] PV -> bar only (no drain).
// ---------------------------------------------------------------------------
__global__ __launch_bounds__(512, 4) void attn_fwd(
    const uint16_t* __restrict__ qhi, const uint16_t* __restrict__ qlo,
    const uint16_t* __restrict__ khi, const uint16_t* __restrict__ klo,
    const uint16_t* __restrict__ vT, uint16_t* __restrict__ oc)
{
    __shared__ __align__(16) char smem[57344];
    // [0,16384): kbuf0  [16384,32768): kbuf1  [32768,40960): vbuf
    // [40960,57344): p_lds (8 waves x 2KB)
    char* __restrict__ vbuf  = smem + 32768;
    char* __restrict__ p_lds = smem + 40960;

    const int bid = blockIdx.x;
    const int qt = (bid >> 3) & 15, bh = (bid & 7) + 8 * (bid >> 7);
    const int tid = threadIdx.x;
    const int l = tid & 63, w = tid >> 6;
    const int g = l >> 4, lm = l & 15;
    const size_t base  = (size_t)bh * (S_LEN * DOUT);
    const size_t vbase = (size_t)bh * (DOUT * S_LEN);

    // staging: thread tid covers LDS bytes [tid*16, tid*16+16) of an 8KB buf;
    // row = tid>>3, slot = tid&7, src col = (slot*8) ^ ((row&7)<<3) elems.
    const int r0 = tid >> 3, sc0 = ((tid & 7) * 8) ^ ((r0 & 7) << 3);

    // Q fragments: lane holds Q[q=lm][d = 32c + 8g + j]
    const int qrow = qt * 128 + w * 16 + lm;
    const uint16_t* qp  = qhi + base + (size_t)qrow * DOUT;
    const uint16_t* qlp = qlo + base + (size_t)qrow * DOUT;
    const bf16x8 qh0 = *(const bf16x8*)(qp + g * 8);
    const bf16x8 qh1 = *(const bf16x8*)(qp + 32 + g * 8);
    const bf16x8 ql0 = *(const bf16x8*)(qlp + g * 8);
    const bf16x8 ql1 = *(const bf16x8*)(qlp + 32 + g * 8);

    const f32x4 Z = {0.f, 0.f, 0.f, 0.f};
    f32x4 O[4] = {Z, Z, Z, Z};
    float m_run = -INFINITY, l_run = 0.f;

    char* __restrict__ pb = p_lds + w * 2048;
    const uint32_t pswz = (uint32_t)((lm & 7) << 4);

    // prologue: stage K(0) into kbuf0 (2 outstanding)
    gload_lds16(khi + base + (size_t)r0 * DOUT + sc0, smem + tid * 16);
    gload_lds16(klo + base + (size_t)r0 * DOUT + sc0, smem + 8192 + tid * 16);

    for (int kt = 0; kt < 32; ++kt) {
        const int cur = kt & 1;
        char* __restrict__ kb = smem + cur * 16384;
        const int s0 = kt * 64;

        // [A] issue V(kt) then K(kt+1) (dummy tile 0 on last iter)
        gload_lds16(vT + vbase + (size_t)r0 * S_LEN + s0 + sc0, vbuf + tid * 16);
        {
            char* __restrict__ kn = smem + (cur ^ 1) * 16384;
            const int sn = (kt < 31) ? s0 + 64 : 0;
            gload_lds16(khi + base + (size_t)(sn + r0) * DOUT + sc0, kn + tid * 16);
            gload_lds16(klo + base + (size_t)(sn + r0) * DOUT + sc0, kn + 8192 + tid * 16);
        }
        // [A'] K(kt) resident (retire oldest 2 of 5); V+Knext stay in flight
        asm volatile("s_waitcnt vmcnt(3)" ::: "memory");
        __builtin_amdgcn_s_barrier();
        __builtin_amdgcn_sched_barrier(0);

        // [B] QK^T (swapped): lane has q=lm, k = 16t + 4g + j
        char* __restrict__ khb = kb;
        char* __restrict__ klb = kb + 8192;
        f32x4 sa[4];
        __builtin_amdgcn_s_setprio(1);
        #pragma unroll
        for (int t = 0; t < 4; ++t) {
            f32x4 a = Z;
            const int kr = t * 16 + lm;
            const uint32_t swz = (uint32_t)((kr & 7) << 4);
            {
                const uint32_t off = ((uint32_t)(kr * 128 + g * 16)) ^ swz;
                const bf16x8 kh = *(const bf16x8*)(khb + off);
                const bf16x8 kl = *(const bf16x8*)(klb + off);
                a = mfma16(kh, qh0, a);
                a = mfma16(kh, ql0, a);
                a = mfma16(kl, qh0, a);
            }
            {
                const uint32_t off = ((uint32_t)(kr * 128 + 64 + g * 16)) ^ swz;
                const bf16x8 kh = *(const bf16x8*)(khb + off);
                const bf16x8 kl = *(const bf16x8*)(klb + off);
                a = mfma16(kh, qh1, a);
                a = mfma16(kh, ql1, a);
                a = mfma16(kl, qh1, a);
            }
            sa[t] = a;
        }
        __builtin_amdgcn_s_setprio(0);

        // online softmax (exp2-domain), defer-max (T13, THR=8)
        float pmax = sa[0][0];
        #pragma unroll
        for (int t = 0; t < 4; ++t)
            #pragma unroll
            for (int j = 0; j < 4; ++j) pmax = fmaxf(pmax, sa[t][j]);
        pmax = fmaxf(pmax, __shfl_xor(pmax, 16));
        pmax = fmaxf(pmax, __shfl_xor(pmax, 32));

        if (!__all(pmax - m_run <= 8.f)) {
            const float m_new = fmaxf(m_run, pmax);
            const float alpha = __builtin_amdgcn_exp2f(m_run - m_new);
            m_run = m_new;
            const float av0 = __shfl(alpha, 4 * g + 0);
            const float av1 = __shfl(alpha, 4 * g + 1);
            const float av2 = __shfl(alpha, 4 * g + 2);
            const float av3 = __shfl(alpha, 4 * g + 3);
            const f32x4 am = {av0, av1, av2, av3};
            #pragma unroll
            for (int dt = 0; dt < 4; ++dt) O[dt] *= am;
            l_run *= alpha;
        }

        float lsum = 0.f;
        uint32_t pk[8];
        #pragma unroll
        for (int t = 0; t < 4; ++t) {
            const float p0 = __builtin_amdgcn_exp2f(sa[t][0] - m_run);
            const float p1 = __builtin_amdgcn_exp2f(sa[t][1] - m_run);
            const float p2 = __builtin_amdgcn_exp2f(sa[t][2] - m_run);
            const float p3 = __builtin_amdgcn_exp2f(sa[t][3] - m_run);
            lsum += (p0 + p1) + (p2 + p3);
            pk[2 * t]     = cvt_pk_bf16(p0, p1);
            pk[2 * t + 1] = cvt_pk_bf16(p2, p3);
        }
        lsum += __shfl_xor(lsum, 16);
        lsum += __shfl_xor(lsum, 32);
        l_run += lsum;

        // P -> wave-private LDS [q][k] bf16
        #pragma unroll
        for (int t = 0; t < 4; ++t) {
            const uint32_t off = ((uint32_t)(lm * 128 + t * 32 + g * 8)) ^ pswz;
            uint2 val; val.x = pk[2 * t]; val.y = pk[2 * t + 1];
            *(uint2*)(pb + off) = val;
        }

        // [C] V(kt) resident (retire oldest of 3); K(kt+1) still in flight
        asm volatile("s_waitcnt vmcnt(2) lgkmcnt(0)" ::: "memory");
        __builtin_amdgcn_s_barrier();
        __builtin_amdgcn_sched_barrier(0);

        // [D] PV: O[16q x 64d] += P[16q x 64k] * V^T rows
        __builtin_amdgcn_s_setprio(1);
        #pragma unroll
        for (int kc = 0; kc < 2; ++kc) {
            const uint32_t poff = ((uint32_t)(lm * 128 + kc * 64 + g * 16)) ^ pswz;
            const bf16x8 pa = *(const bf16x8*)(pb + poff);
            #pragma unroll
            for (int dt = 0; dt < 4; ++dt) {
                const int vr = dt * 16 + lm;
                const uint32_t voff = (uint32_t)(vr * 128 + ((kc * 64 + g * 16) ^ ((vr & 7) << 4)));
                const bf16x8 vb = *(const bf16x8*)(vbuf + voff);
                O[dt] = mfma16(pa, vb, O[dt]);
            }
        }
        __builtin_amdgcn_s_setprio(0);

        // [E] protect vbuf from next iter's DMA; NO vmcnt -> K stays in flight
        __builtin_amdgcn_s_barrier();
        __builtin_amdgcn_sched_barrier(0);
    }

    // epilogue: normalize, write o_concat[b][s][h*64+d] bf16
    const int b = bh >> 3, hh = bh & 7;
    #pragma unroll
    for (int j = 0; j < 4; ++j) {
        const float li = 1.f / __shfl(l_run, 4 * g + j);
        const int srow = qt * 128 + w * 16 + 4 * g + j;
        const size_t rbase = ((size_t)b * S_LEN + srow) * (NH * DOUT) + hh * DOUT;
        #pragma unroll
        for (int dt = 0; dt < 4; ++dt)
            oc[rbase + dt * 16 + lm] = f2bf(O[dt][j] * li);
    }
}

// ---------------------------------------------------------------------------
// Kernel 6: output projection out = o_concat[8192x512] @ wo[512x64], fp32 out.
// ---------------------------------------------------------------------------
__global__ __launch_bounds__(256) void oproj(
    const uint16_t* __restrict__ oc, const uint16_t* __restrict__ woT,
    float* __restrict__ out)
{
    const int mt = blockIdx.x;
    const int tid = threadIdx.x;
    const int l = tid & 63, w = tid >> 6;
    const int g = l >> 4, lm = l & 15;
    const int m0 = mt * 64 + w * 16;
    const f32x4 Z = {0.f, 0.f, 0.f, 0.f};
    f32x4 acc[4] = {Z, Z, Z, Z};
    const uint16_t* __restrict__ arow = oc + (size_t)(m0 + lm) * (NH * DOUT);
    for (int kc = 0; kc < 16; ++kc) {
        const bf16x8 a = *(const bf16x8*)(arow + kc * 32 + g * 8);
        #pragma unroll
        for (int nt = 0; nt < 4; ++nt) {
            const bf16x8 bfr = *(const bf16x8*)(woT + (size_t)(nt * 16 + lm) * (NH * DOUT) + kc * 32 + g * 8);
            acc[nt] = mfma16(a, bfr, acc[nt]);
        }
    }
    #pragma unroll
    for (int nt = 0; nt < 4; ++nt)
        #pragma unroll
        for (int j = 0; j < 4; ++j)
            out[(size_t)(m0 + 4 * g + j) * DOUT + nt * 16 + lm] = acc[nt][j];
}

// ---------------------------------------------------------------------------
extern "C" void kernel_launch(void* const* d_in, const int* in_sizes, int n_in,
                              void* d_out, int out_size, void* d_ws, size_t ws_size,
                              hipStream_t stream) {
    const float* x  = (const float*)d_in[0];
    const float* w  = (const float*)d_in[1];
    const float* wo = (const float*)d_in[2];
    float* out = (float*)d_out;

    char* ws = (char*)d_ws;
    uint16_t* qhi  = (uint16_t*)(ws);              // 8388608 B each
    uint16_t* qlo  = (uint16_t*)(ws + 8388608);
    uint16_t* khi  = (uint16_t*)(ws + 16777216);
    uint16_t* klo  = (uint16_t*)(ws + 25165824);
    uint16_t* vbf  = (uint16_t*)(ws + 33554432);
    uint16_t* xhi  = (uint16_t*)(ws + 41943040);   // 8388608 B
    uint16_t* xlo  = (uint16_t*)(ws + 50331648);   // 8388608 B
    uint16_t* whiT = (uint16_t*)(ws + 58720256);   // 1572864 B
    uint16_t* wloT = (uint16_t*)(ws + 60293120);
    uint16_t* woT  = (uint16_t*)(ws + 61865984);   // 65536 B
    // aliases: oc over xhi, vT over xlo (both dead after gemm_qkv; split_x
    // rewrites them every call before gemm_qkv reads them).
    uint16_t* oc   = xhi;
    uint16_t* vT   = xlo;

    hipLaunchKernelGGL(prep_w, dim3(200), dim3(256), 0, stream, w, wo, whiT, wloT, woT);
    hipLaunchKernelGGL(split_x, dim3(2048), dim3(256), 0, stream, x, xhi, xlo);
    hipLaunchKernelGGL(gemm_qkv, dim3(768), dim3(256), 0, stream,
                       xhi, xlo, whiT, wloT, qhi, qlo, khi, klo, vbf);
    hipLaunchKernelGGL(transpose_v, dim3(32, 32), dim3(256), 0, stream, vbf, vT);
    hipLaunchKernelGGL(attn_fwd, dim3(512), dim3(512), 0, stream,
                       qhi, qlo, khi, klo, vT, oc);
    hipLaunchKernelGGL(oproj, dim3(128), dim3(256), 0, stream, oc, woT, out);
}

// Round 6
// 159.349 us; speedup vs baseline: 2.3764x; 1.0726x over previous
//
#include <hip/hip_runtime.h>
#include <cstdint>
#include <cstddef>

#define S_LEN 2048
#define DIN   512
#define DOUT  64
#define NB    4
#define NH    8

typedef __attribute__((ext_vector_type(8))) short bf16x8;
typedef __attribute__((ext_vector_type(4))) float f32x4;
typedef __attribute__((ext_vector_type(16))) float f32x16;

static __device__ __forceinline__ f32x4 mfma16(bf16x8 a, bf16x8 b, f32x4 c) {
    return __builtin_amdgcn_mfma_f32_16x16x32_bf16(a, b, c, 0, 0, 0);
}
static __device__ __forceinline__ f32x16 mfma32(bf16x8 a, bf16x8 b, f32x16 c) {
    return __builtin_amdgcn_mfma_f32_32x32x16_bf16(a, b, c, 0, 0, 0);
}

static __device__ __forceinline__ uint16_t f2bf(float x) {
    uint32_t u = __builtin_bit_cast(uint32_t, x);
    u += 0x7fffu + ((u >> 16) & 1u);
    return (uint16_t)(u >> 16);
}
static __device__ __forceinline__ float bf2f(uint16_t h) {
    uint32_t u = ((uint32_t)h) << 16;
    return __builtin_bit_cast(float, u);
}
static __device__ __forceinline__ uint32_t cvt_pk_bf16(float lo, float hi) {
    uint32_t r;
    asm("v_cvt_pk_bf16_f32 %0, %1, %2" : "=v"(r) : "v"(lo), "v"(hi));
    return r;
}

typedef const __attribute__((address_space(1))) void* as1p;
typedef __attribute__((address_space(3))) void* as3p;
static __device__ __forceinline__ void gload_lds16(const void* g, void* l) {
    __builtin_amdgcn_global_load_lds((as1p)g, (as3p)l, 16, 0, 0);
}

// ---------------------------------------------------------------------------
// Kernel 1: weight prep via LDS transpose (coalesced both sides).
// ---------------------------------------------------------------------------
__global__ __launch_bounds__(256) void prep_w(
    const float* __restrict__ w, const float* __restrict__ wo,
    uint16_t* __restrict__ whiT, uint16_t* __restrict__ wloT,
    uint16_t* __restrict__ woT)
{
    __shared__ float tile[64][65];
    const int blk = blockIdx.x;
    const int t = threadIdx.x;
    const int tq = t >> 6, tr = t & 63;

    if (blk < 192) {
        const int hp = blk >> 3, i0 = (blk & 7) * 64;
        const int p = hp % 3;
        const float s = (p == 0) ? 0.18033688011112042f : 1.0f; // 0.125*log2(e)
        const float* __restrict__ src = w + (size_t)hp * (DIN * DOUT);
        #pragma unroll
        for (int r = 0; r < 16; ++r) {
            const int ir = r * 4 + tq;
            tile[ir][tr] = src[(size_t)(i0 + ir) * DOUT + tr];
        }
        __syncthreads();
        uint16_t* __restrict__ dh = whiT + (size_t)hp * (DOUT * DIN);
        uint16_t* __restrict__ dl = wloT + (size_t)hp * (DOUT * DIN);
        #pragma unroll
        for (int r = 0; r < 16; ++r) {
            const int o = r * 4 + tq;
            const float v = tile[tr][o] * s;
            const uint16_t hi = f2bf(v);
            dh[(size_t)o * DIN + i0 + tr] = hi;
            dl[(size_t)o * DIN + i0 + tr] = f2bf(v - bf2f(hi));
        }
    } else {
        const int i0 = (blk - 192) * 64;
        #pragma unroll
        for (int r = 0; r < 16; ++r) {
            const int ir = r * 4 + tq;
            tile[ir][tr] = wo[(size_t)(i0 + ir) * DOUT + tr];
        }
        __syncthreads();
        #pragma unroll
        for (int r = 0; r < 16; ++r) {
            const int o = r * 4 + tq;
            woT[(size_t)o * DIN + i0 + tr] = f2bf(tile[tr][o]);
        }
    }
}

// ---------------------------------------------------------------------------
// Kernel 2: split x [8192][512] fp32 -> xhi/xlo bf16 (vectorized, one pass).
// ---------------------------------------------------------------------------
__global__ __launch_bounds__(256) void split_x(
    const float* __restrict__ x, uint16_t* __restrict__ xhi, uint16_t* __restrict__ xlo)
{
    const size_t idx = ((size_t)blockIdx.x * 256 + threadIdx.x) * 8;
    const float4 a = *(const float4*)(x + idx);
    const float4 b = *(const float4*)(x + idx + 4);
    const float xv[8] = {a.x, a.y, a.z, a.w, b.x, b.y, b.z, b.w};
    union { uint16_t u[8]; uint4 v; } H, L;
    #pragma unroll
    for (int j = 0; j < 8; ++j) {
        const uint16_t hi = f2bf(xv[j]);
        H.u[j] = hi;
        L.u[j] = f2bf(xv[j] - bf2f(hi));
    }
    *(uint4*)(xhi + idx) = H.v;
    *(uint4*)(xlo + idx) = L.v;
}

// ---------------------------------------------------------------------------
// Kernel 3: QKV projection GEMM (m97 structure). V written pre-transposed:
// vT[bh][d][s] (kills the standalone transpose kernel).
// ---------------------------------------------------------------------------
__global__ __launch_bounds__(256) void gemm_qkv(
    const uint16_t* __restrict__ xhi, const uint16_t* __restrict__ xlo,
    const uint16_t* __restrict__ whiT, const uint16_t* __restrict__ wloT,
    uint16_t* __restrict__ qhi, uint16_t* __restrict__ qlo,
    uint16_t* __restrict__ khi, uint16_t* __restrict__ klo,
    uint16_t* __restrict__ vT)
{
    __shared__ __align__(16) uint16_t lds[2 * 128 * 64];

    const int bid = blockIdx.x;
    const int xcd = bid & 7, wi = bid >> 3;
    const int mt = xcd * 8 + wi / 12, nt = wi % 12;
    const int m0 = mt * 128, n0 = nt * 128;
    const int tid = threadIdx.x;
    const int l = tid & 63, w = tid >> 6;
    const int g = l >> 4, lm = l & 15;
    const int wm = w >> 1, wn = w & 1;

    const f32x4 Z = {0.f, 0.f, 0.f, 0.f};
    f32x4 acc[4][4];
    #pragma unroll
    for (int a = 0; a < 4; ++a)
        #pragma unroll
        for (int b = 0; b < 4; ++b) acc[a][b] = Z;

    int srow[4], scol[4];
    #pragma unroll
    for (int i = 0; i < 4; ++i) {
        const int c = i * 256 + tid;
        srow[i] = c >> 3;
        scol[i] = ((c & 7) * 8) ^ ((srow[i] & 7) << 3);
    }

    for (int kt = 0; kt < 24; ++kt) {
        const int k0 = (kt & 7) * 64;
        const uint16_t* __restrict__ As = (kt < 16) ? xhi : xlo;
        const uint16_t* __restrict__ Bs = (kt >= 8 && kt < 16) ? wloT : whiT;
        #pragma unroll
        for (int i = 0; i < 4; ++i) {
            const int c8 = (i * 256 + tid) * 8;
            gload_lds16(As + (size_t)(m0 + srow[i]) * DIN + k0 + scol[i], &lds[c8]);
            gload_lds16(Bs + (size_t)(n0 + srow[i]) * DIN + k0 + scol[i], &lds[128 * 64 + c8]);
        }
        asm volatile("s_waitcnt vmcnt(0)" ::: "memory");
        __syncthreads();

        bf16x8 af[4][2];
        #pragma unroll
        for (int mi = 0; mi < 4; ++mi) {
            const int r = wm * 64 + mi * 16 + lm;
            const int rb = r * 128;
            #pragma unroll
            for (int kk = 0; kk < 2; ++kk) {
                const int cb = (kk * 64 + g * 16) ^ ((r & 7) << 4);
                af[mi][kk] = *(const bf16x8*)((const char*)lds + rb + cb);
            }
        }
        #pragma unroll
        for (int ni = 0; ni < 4; ++ni) {
            const int r = wn * 64 + ni * 16 + lm;
            const int rb = 128 * 64 * 2 + r * 128;
            bf16x8 bfr[2];
            #pragma unroll
            for (int kk = 0; kk < 2; ++kk) {
                const int cb = (kk * 64 + g * 16) ^ ((r & 7) << 4);
                bfr[kk] = *(const bf16x8*)((const char*)lds + rb + cb);
            }
            #pragma unroll
            for (int mi = 0; mi < 4; ++mi) {
                acc[mi][ni] = mfma16(af[mi][0], bfr[0], acc[mi][ni]);
                acc[mi][ni] = mfma16(af[mi][1], bfr[1], acc[mi][ni]);
            }
        }
        __syncthreads();
    }

    #pragma unroll
    for (int ni = 0; ni < 4; ++ni) {
        const int n = n0 + wn * 64 + ni * 16 + lm;
        const int hp = n >> 6, o = n & 63;
        const int h = hp / 3, p = hp - h * 3;
        if (p < 2) {
            uint16_t* __restrict__ dhi = (p == 0) ? qhi : khi;
            uint16_t* __restrict__ dlo = (p == 0) ? qlo : klo;
            #pragma unroll
            for (int mi = 0; mi < 4; ++mi) {
                #pragma unroll
                for (int j = 0; j < 4; ++j) {
                    const int m = m0 + wm * 64 + mi * 16 + 4 * g + j;
                    const int b = m >> 11, s = m & 2047;
                    const size_t idx = ((size_t)(b * NH + h) * S_LEN + s) * DOUT + o;
                    const float v = acc[mi][ni][j];
                    const uint16_t hi = f2bf(v);
                    dhi[idx] = hi;
                    dlo[idx] = f2bf(v - bf2f(hi));
                }
            }
        } else {
            #pragma unroll
            for (int mi = 0; mi < 4; ++mi) {
                const int m = m0 + wm * 64 + mi * 16 + 4 * g;  // 4 consecutive s
                const int b = m >> 11, s = m & 2047;
                uint2 val;
                val.x = cvt_pk_bf16(acc[mi][ni][0], acc[mi][ni][1]);
                val.y = cvt_pk_bf16(acc[mi][ni][2], acc[mi][ni][3]);
                *(uint2*)(vT + ((size_t)((b * NH + h) * DOUT + o)) * S_LEN + s) = val;
            }
        }
    }
}

// ---------------------------------------------------------------------------
// Kernel 4: flash attention, 32x32 MFMA, in-register softmax (T12), no P-LDS.
//   grid 512 x 256thr (4 waves, 32 q-rows each, QBLK=128); KV tile 64.
//   Swapped QK: mfma32(K,Q) -> lane holds S[k-rows][q=lane&31]; max/sum/
//   rescale lane-local + one shfl_xor(32). P -> B-fragment via cvt_pk +
//   v_permlane32_swap (VDST = lower-reg pack!). PV computes O^T[d][q].
//   R4's counted-vmcnt no-drain pipeline retained (K dbuf + V single).
// ---------------------------------------------------------------------------
__global__ __launch_bounds__(256, 2) void attn_fwd(
    const uint16_t* __restrict__ qhi, const uint16_t* __restrict__ qlo,
    const uint16_t* __restrict__ khi, const uint16_t* __restrict__ klo,
    const uint16_t* __restrict__ vT, uint16_t* __restrict__ oc)
{
    __shared__ __align__(16) char smem[40960];
    // [0,16384): kbuf0 (khi 8K | klo 8K)  [16384,32768): kbuf1  [32768,40960): vbuf
    char* __restrict__ vbuf = smem + 32768;

    const int bid = blockIdx.x;
    const int qt = (bid >> 3) & 15, bh = (bid & 7) + 8 * (bid >> 7);
    const int tid = threadIdx.x;
    const int l = tid & 63, wq = tid >> 6;
    const int L = l >> 5, lq = l & 31;
    const size_t base = (size_t)bh * (S_LEN * DOUT);

    // staging: chunk c -> LDS byte c*16; row=c>>3, src col=((c&7)*8)^((row&7)<<3)
    const int c0 = tid, c1 = tid + 256;
    const int r0 = c0 >> 3, sc0 = ((c0 & 7) * 8) ^ ((r0 & 7) << 3);
    const int r1 = c1 >> 3, sc1 = ((c1 & 7) * 8) ^ ((r1 & 7) << 3);

    // Q B-fragments: lane holds Q[q = qrow][d = dsub*16 + 8L + j]
    const int qrow = qt * 128 + wq * 32 + lq;
    const uint16_t* qp  = qhi + base + (size_t)qrow * DOUT;
    const uint16_t* qlp = qlo + base + (size_t)qrow * DOUT;
    bf16x8 qh[4], qlf[4];
    #pragma unroll
    for (int dsub = 0; dsub < 4; ++dsub) {
        qh[dsub]  = *(const bf16x8*)(qp  + dsub * 16 + L * 8);
        qlf[dsub] = *(const bf16x8*)(qlp + dsub * 16 + L * 8);
    }

    f32x16 Zv;
    #pragma unroll
    for (int r = 0; r < 16; ++r) Zv[r] = 0.f;
    f32x16 Oa[2] = {Zv, Zv};           // O^T[d = dh*32 + row(reg,L)][q = lq]
    float m_run = -INFINITY, l_run = 0.f;

    // prologue: K(0) -> kbuf0 (4 outstanding)
    gload_lds16(khi + base + (size_t)r0 * DOUT + sc0, smem + c0 * 16);
    gload_lds16(khi + base + (size_t)r1 * DOUT + sc1, smem + c1 * 16);
    gload_lds16(klo + base + (size_t)r0 * DOUT + sc0, smem + 8192 + c0 * 16);
    gload_lds16(klo + base + (size_t)r1 * DOUT + sc1, smem + 8192 + c1 * 16);

    for (int kt = 0; kt < 32; ++kt) {
        const int cur = kt & 1;
        char* __restrict__ kb = smem + cur * 16384;
        const int s0 = kt * 64;

        // [A] issue V(kt) then K(kt+1) (dummy tile 0 on last iter)
        gload_lds16(vT + base + (size_t)r0 * S_LEN + s0 + sc0, vbuf + c0 * 16);
        gload_lds16(vT + base + (size_t)r1 * S_LEN + s0 + sc1, vbuf + c1 * 16);
        {
            char* __restrict__ kn = smem + (cur ^ 1) * 16384;
            const int sn = (kt < 31) ? s0 + 64 : 0;
            gload_lds16(khi + base + (size_t)(sn + r0) * DOUT + sc0, kn + c0 * 16);
            gload_lds16(khi + base + (size_t)(sn + r1) * DOUT + sc1, kn + c1 * 16);
            gload_lds16(klo + base + (size_t)(sn + r0) * DOUT + sc0, kn + 8192 + c0 * 16);
            gload_lds16(klo + base + (size_t)(sn + r1) * DOUT + sc1, kn + 8192 + c1 * 16);
        }
        // K(kt) resident (retire oldest 4 of 10); V + K(next) in flight
        asm volatile("s_waitcnt vmcnt(6)" ::: "memory");
        __builtin_amdgcn_s_barrier();
        __builtin_amdgcn_sched_barrier(0);

        // [B] QK^T: sa[ks] holds S[k = ks*32 + (reg&3)+8(reg>>2)+4L][q = lq]
        f32x16 sa[2];
        __builtin_amdgcn_s_setprio(1);
        #pragma unroll
        for (int ks = 0; ks < 2; ++ks) {
            const int kr = ks * 32 + lq;
            const uint32_t rb = (uint32_t)(kr * 128);
            const uint32_t swz = (uint32_t)((kr & 7) << 4);
            f32x16 s = Zv;
            #pragma unroll
            for (int dsub = 0; dsub < 4; ++dsub) {
                const uint32_t off = rb + (((uint32_t)(dsub * 32 + L * 16)) ^ swz);
                const bf16x8 kh = *(const bf16x8*)(kb + off);
                const bf16x8 kl = *(const bf16x8*)(kb + 8192 + off);
                s = mfma32(kh, qh[dsub], s);
                s = mfma32(kh, qlf[dsub], s);
                s = mfma32(kl, qh[dsub], s);
            }
            sa[ks] = s;
        }
        __builtin_amdgcn_s_setprio(0);

        // ---- softmax: all 32 in-lane values are the SAME q-row
        float pmax = sa[0][0];
        #pragma unroll
        for (int ks = 0; ks < 2; ++ks)
            #pragma unroll
            for (int r = 0; r < 16; ++r) pmax = fmaxf(pmax, sa[ks][r]);
        pmax = fmaxf(pmax, __shfl_xor(pmax, 32));

        if (!__all(pmax - m_run <= 8.f)) {
            const float m_new = fmaxf(m_run, pmax);
            const float alpha = __builtin_amdgcn_exp2f(m_run - m_new);
            m_run = m_new;
            #pragma unroll
            for (int r = 0; r < 16; ++r) { Oa[0][r] *= alpha; Oa[1][r] *= alpha; }
            l_run *= alpha;
        }

        float lsum = 0.f;
        #pragma unroll
        for (int ks = 0; ks < 2; ++ks)
            #pragma unroll
            for (int r = 0; r < 16; ++r) {
                const float pv = __builtin_amdgcn_exp2f(sa[ks][r] - m_run);
                sa[ks][r] = pv;
                lsum += pv;
            }
        lsum += __shfl_xor(lsum, 32);
        l_run += lsum;

        // ---- pack P into PV B-fragments: pfrag[kc] = P[k = kc*16 + 8L + j][q]
        // permlane32_swap(VDST=lo_pack, VSRC=hi_pack):
        //   new lo: L=0 keeps own, L=1 gets partner's hi  -> word w0/w1
        //   new hi: L=0 gets partner's lo, L=1 keeps own  -> word w2/w3
        bf16x8 pfrag[4];
        #pragma unroll
        for (int ks = 0; ks < 2; ++ks) {
            uint32_t a0 = cvt_pk_bf16(sa[ks][0], sa[ks][1]);
            uint32_t a1 = cvt_pk_bf16(sa[ks][2], sa[ks][3]);
            uint32_t a2 = cvt_pk_bf16(sa[ks][4], sa[ks][5]);
            uint32_t a3 = cvt_pk_bf16(sa[ks][6], sa[ks][7]);
            asm volatile("v_permlane32_swap_b32 %0, %1" : "+v"(a0), "+v"(a2));
            asm volatile("v_permlane32_swap_b32 %0, %1" : "+v"(a1), "+v"(a3));
            union { uint32_t w[4]; bf16x8 v; } u;
            u.w[0] = a0; u.w[1] = a1; u.w[2] = a2; u.w[3] = a3;
            pfrag[2 * ks] = u.v;
            uint32_t b0 = cvt_pk_bf16(sa[ks][8],  sa[ks][9]);
            uint32_t b1 = cvt_pk_bf16(sa[ks][10], sa[ks][11]);
            uint32_t b2 = cvt_pk_bf16(sa[ks][12], sa[ks][13]);
            uint32_t b3 = cvt_pk_bf16(sa[ks][14], sa[ks][15]);
            asm volatile("v_permlane32_swap_b32 %0, %1" : "+v"(b0), "+v"(b2));
            asm volatile("v_permlane32_swap_b32 %0, %1" : "+v"(b1), "+v"(b3));
            union { uint32_t w[4]; bf16x8 v; } u2;
            u2.w[0] = b0; u2.w[1] = b1; u2.w[2] = b2; u2.w[3] = b3;
            pfrag[2 * ks + 1] = u2.v;
        }

        // [C] V(kt) resident (retire oldest 2 of 6); K(kt+1) stays in flight
        asm volatile("s_waitcnt vmcnt(4)" ::: "memory");
        __builtin_amdgcn_s_barrier();
        __builtin_amdgcn_sched_barrier(0);

        // [D] PV: O^T[d][q] += V^T-frag . pfrag   (A rows d, B cols q)
        __builtin_amdgcn_s_setprio(1);
        #pragma unroll
        for (int dh = 0; dh < 2; ++dh) {
            const int dr = dh * 32 + lq;
            const uint32_t rb = (uint32_t)(dr * 128);
            const uint32_t swz = (uint32_t)((dr & 7) << 4);
            #pragma unroll
            for (int kc = 0; kc < 4; ++kc) {
                const uint32_t off = rb + (((uint32_t)(kc * 32 + L * 16)) ^ swz);
                const bf16x8 vv = *(const bf16x8*)(vbuf + off);
                Oa[dh] = mfma32(vv, pfrag[kc], Oa[dh]);
            }
        }
        __builtin_amdgcn_s_setprio(0);

        // [E] protect vbuf/kbuf from next iter's DMA; NO vmcnt drain
        __builtin_amdgcn_s_barrier();
        __builtin_amdgcn_sched_barrier(0);
    }

    // epilogue: lane-local normalize; O^T -> oc[b][s][h*64+d], 8B packed
    const int b = bh >> 3, hh = bh & 7;
    const float li = 1.f / l_run;
    const int srow = qt * 128 + wq * 32 + lq;
    const size_t rbase = ((size_t)b * S_LEN + srow) * (NH * DOUT) + hh * DOUT;
    #pragma unroll
    for (int dh = 0; dh < 2; ++dh) {
        #pragma unroll
        for (int rq = 0; rq < 4; ++rq) {
            const int d0 = dh * 32 + rq * 8 + L * 4;
            uint2 val;
            val.x = cvt_pk_bf16(Oa[dh][rq * 4 + 0] * li, Oa[dh][rq * 4 + 1] * li);
            val.y = cvt_pk_bf16(Oa[dh][rq * 4 + 2] * li, Oa[dh][rq * 4 + 3] * li);
            *(uint2*)(oc + rbase + d0) = val;
        }
    }
}

// ---------------------------------------------------------------------------
// Kernel 5: output projection out = o_concat[8192x512] @ wo[512x64], fp32 out.
// ---------------------------------------------------------------------------
__global__ __launch_bounds__(256) void oproj(
    const uint16_t* __restrict__ oc, const uint16_t* __restrict__ woT,
    float* __restrict__ out)
{
    const int mt = blockIdx.x;
    const int tid = threadIdx.x;
    const int l = tid & 63, w = tid >> 6;
    const int g = l >> 4, lm = l & 15;
    const int m0 = mt * 64 + w * 16;
    const f32x4 Z = {0.f, 0.f, 0.f, 0.f};
    f32x4 acc[4] = {Z, Z, Z, Z};
    const uint16_t* __restrict__ arow = oc + (size_t)(m0 + lm) * (NH * DOUT);
    for (int kc = 0; kc < 16; ++kc) {
        const bf16x8 a = *(const bf16x8*)(arow + kc * 32 + g * 8);
        #pragma unroll
        for (int nt = 0; nt < 4; ++nt) {
            const bf16x8 bfr = *(const bf16x8*)(woT + (size_t)(nt * 16 + lm) * (NH * DOUT) + kc * 32 + g * 8);
            acc[nt] = mfma16(a, bfr, acc[nt]);
        }
    }
    #pragma unroll
    for (int nt = 0; nt < 4; ++nt)
        #pragma unroll
        for (int j = 0; j < 4; ++j)
            out[(size_t)(m0 + 4 * g + j) * DOUT + nt * 16 + lm] = acc[nt][j];
}

// ---------------------------------------------------------------------------
extern "C" void kernel_launch(void* const* d_in, const int* in_sizes, int n_in,
                              void* d_out, int out_size, void* d_ws, size_t ws_size,
                              hipStream_t stream) {
    const float* x  = (const float*)d_in[0];
    const float* w  = (const float*)d_in[1];
    const float* wo = (const float*)d_in[2];
    float* out = (float*)d_out;

    char* ws = (char*)d_ws;
    uint16_t* qhi  = (uint16_t*)(ws);              // 8388608 B each
    uint16_t* qlo  = (uint16_t*)(ws + 8388608);
    uint16_t* khi  = (uint16_t*)(ws + 16777216);
    uint16_t* klo  = (uint16_t*)(ws + 25165824);
    uint16_t* vT   = (uint16_t*)(ws + 33554432);   // [B*H][64][2048] bf16
    uint16_t* xhi  = (uint16_t*)(ws + 41943040);   // 8388608 B
    uint16_t* xlo  = (uint16_t*)(ws + 50331648);   // 8388608 B
    uint16_t* whiT = (uint16_t*)(ws + 58720256);   // 1572864 B
    uint16_t* wloT = (uint16_t*)(ws + 60293120);
    uint16_t* woT  = (uint16_t*)(ws + 61865984);   // 65536 B
    // oc aliases xhi (dead after gemm_qkv; split_x rewrites it every call).
    uint16_t* oc   = xhi;

    hipLaunchKernelGGL(prep_w, dim3(200), dim3(256), 0, stream, w, wo, whiT, wloT, woT);
    hipLaunchKernelGGL(split_x, dim3(2048), dim3(256), 0, stream, x, xhi, xlo);
    hipLaunchKernelGGL(gemm_qkv, dim3(768), dim3(256), 0, stream,
                       xhi, xlo, whiT, wloT, qhi, qlo, khi, klo, vT);
    hipLaunchKernelGGL(attn_fwd, dim3(512), dim3(256), 0, stream,
                       qhi, qlo, khi, klo, vT, oc);
    hipLaunchKernelGGL(oproj, dim3(128), dim3(256), 0, stream, oc, woT, out);
}